// Round 7
// baseline (1022.555 us; speedup 1.0000x reference)
//
#include <hip/hip_runtime.h>
#include <hip/hip_bf16.h>
#include <cstddef>

#define N_NODES 10000
#define KNBR 32
#define HDIM 128
#define NHEADS 8

using short8 = __attribute__((ext_vector_type(8))) short;
using short4v = __attribute__((ext_vector_type(4))) short;
using f32x4 = __attribute__((ext_vector_type(4))) float;

__device__ __forceinline__ f32x4 mfma16(short8 a, short8 b, f32x4 c) {
  return __builtin_amdgcn_mfma_f32_16x16x32_bf16(a, b, c, 0, 0, 0);
}

// HW bf16 convert (RNE)
__device__ __forceinline__ short f2bf(float f) {
  __hip_bfloat16 h = __float2bfloat16(f);
  return __builtin_bit_cast(short, h);
}
__device__ __forceinline__ float bf2f(short s) {
  unsigned u = ((unsigned)(unsigned short)s) << 16;
  return __builtin_bit_cast(float, u);
}

// tanh-approx gelu == x * sigmoid(1.59577x + 0.0713548x^3), exp folded into
// exp2 (v_exp_f32) + v_rcp_f32: ~7 VALU ops vs ~15 for the 2-2/(e+1) form
// (which compiles to a precise divide without fast-math).
__device__ __forceinline__ float gelu_f(float x) {
  float u = x * fmaf(x * x, -0.1029432f, -2.3022077f);
  return x * __builtin_amdgcn_rcpf(1.0f + __builtin_amdgcn_exp2f(u));
}

__device__ __forceinline__ short4v pack4f(float a, float b, float c, float d) {
  short4v v; v[0] = f2bf(a); v[1] = f2bf(b); v[2] = f2bf(c); v[3] = f2bf(d);
  return v;
}
__device__ __forceinline__ short4v pack_gelu4(f32x4 acc, float4 bb) {
  return pack4f(gelu_f(acc[0] + bb.x), gelu_f(acc[1] + bb.y),
                gelu_f(acc[2] + bb.z), gelu_f(acc[3] + bb.w));
}

// Swizzled LDS tiles: row-major [rows][128 or 256] bf16, 16B chunk c of row r
// stored at physical chunk (c ^ (r&7)). Conflict-free A-frag ds_read_b128.
__device__ __forceinline__ short8 ld_sw128(const short* b, int r, int ch) {
  return *(const short8*)(b + r * 128 + (((ch ^ (r & 7))) << 3));
}
__device__ __forceinline__ short8 ld_sw256(const short* b, int r, int ch) {
  return *(const short8*)(b + r * 256 + (((ch ^ (r & 7))) << 3));
}
__device__ __forceinline__ void st_sw128(short* b, int r, int col, short v) {
  b[r * 128 + ((((col >> 3) ^ (r & 7))) << 3) + (col & 7)] = v;
}
// b64 store of 4 consecutive cols (colb aligned to 4) of row r
__device__ __forceinline__ void st_sw128_v4(short* b, int r, int colb, short4v v) {
  *(short4v*)(b + r * 128 + ((((colb >> 3) ^ (r & 7))) << 3) + (colb & 7)) = v;
}
__device__ __forceinline__ void st_sw256_v4(short* b, int r, int colb, short4v v) {
  *(short4v*)(b + r * 256 + ((((colb >> 3) ^ (r & 7))) << 3) + (colb & 7)) = v;
}

// Per-wave MFMA GEMM, A-PRELOAD form (R3-proven: all A-frags resident ->
// compiler keeps multiple global B-loads in flight; k-outer minimal-reg form
// (R4/R5) serialized B-load->MFMA and lost ~60-80us of ILP).
// Normal orientation: epi acc[rr] = C[row = mt*16 + lq*4 + rr][col = nt*16 + lm].
template <int MT, int NT, int KS, typename ALoad, typename Epi>
__device__ __forceinline__ void wgemm(ALoad aload, const short* __restrict__ Bt,
                                      Epi epi) {
  const int lane = threadIdx.x & 63;
  const int lm = lane & 15, lq = lane >> 4;
  short8 a[MT][KS];
#pragma unroll
  for (int mt = 0; mt < MT; ++mt)
#pragma unroll
    for (int k = 0; k < KS; ++k) a[mt][k] = aload(mt * 16 + lm, k, lq);
#pragma unroll
  for (int nt = 0; nt < NT; ++nt) {
    short8 b[KS];
#pragma unroll
    for (int k = 0; k < KS; ++k)
      b[k] = *(const short8*)(Bt + (nt * 16 + lm) * (KS * 32) + k * 32 + lq * 8);
#pragma unroll
    for (int mt = 0; mt < MT; ++mt) {
      f32x4 acc = {0.f, 0.f, 0.f, 0.f};
#pragma unroll
      for (int k = 0; k < KS; ++k) acc = mfma16(a[mt][k], b[k], acc);
      epi(mt, nt, acc);
    }
  }
}

// Transposed-output variant, same A-PRELOAD internals, operands swapped
// (legal: A/B fragment layouts symmetric; verified R5). Lane holds 4
// CONSECUTIVE COLUMNS: epi acc[rr] = C[row = mt*16+lm][col = nt*16+lq*4+rr].
template <int MT, int NT, int KS, typename ALoad, typename Epi>
__device__ __forceinline__ void wgemm_t(ALoad aload, const short* __restrict__ Bt,
                                        Epi epi) {
  const int lane = threadIdx.x & 63;
  const int lm = lane & 15, lq = lane >> 4;
  short8 a[MT][KS];
#pragma unroll
  for (int mt = 0; mt < MT; ++mt)
#pragma unroll
    for (int k = 0; k < KS; ++k) a[mt][k] = aload(mt * 16 + lm, k, lq);
#pragma unroll
  for (int nt = 0; nt < NT; ++nt) {
    short8 b[KS];
#pragma unroll
    for (int k = 0; k < KS; ++k)
      b[k] = *(const short8*)(Bt + (nt * 16 + lm) * (KS * 32) + k * 32 + lq * 8);
#pragma unroll
    for (int mt = 0; mt < MT; ++mt) {
      f32x4 acc = {0.f, 0.f, 0.f, 0.f};
#pragma unroll
      for (int k = 0; k < KS; ++k) acc = mfma16(b[k], a[mt][k], acc);
      epi(mt, nt, acc);
    }
  }
}

// ---------------- kernel 0: weights -> bf16 transposed in ws ----------------
struct WSrc { const float* p[9]; };

__global__ void wprep_kernel(WSrc ws, short* __restrict__ dst) {
  const int cum[10] = {0, 16384, 49152, 81920, 131072, 147456, 180224, 212992, 245760, 278528};
  const int Ks[9] = {128, 256, 256, 128, 128, 128, 256, 128, 256};
  const int Ns[9] = {128, 128, 128, 384, 128, 256, 128, 256, 128};
  int eg = blockIdx.x * 256 + threadIdx.x;
  int id = 0;
#pragma unroll
  for (int i = 0; i < 8; ++i) id += (eg >= cum[i + 1]) ? 1 : 0;
  int e = eg - cum[id];
  int K = Ks[id];
  int n = (K == 128) ? (e >> 7) : (e >> 8);
  int k = e - n * K;
  dst[eg] = f2bf(ws.p[id][k * Ns[id] + n]);
}

// ---------------- kernel 1: LN(node_features) -> bf16 ws0 ----------------
__global__ __launch_bounds__(256) void ln_in_kernel(
    const float* __restrict__ in, const float* __restrict__ g,
    const float* __restrict__ be, short* __restrict__ out) {
  __shared__ float scr[32 * 8 * 2 + 64];
  const int tid = threadIdx.x;
  const int r = tid >> 3, j = tid & 7;
  const int base = blockIdx.x * 32;
  const int rg = base + r;
  const bool valid = rg < N_NODES;
  float4 v[4];
#pragma unroll
  for (int i = 0; i < 4; ++i)
    v[i] = valid ? ((const float4*)(in + (size_t)rg * 128 + j * 16))[i]
                 : make_float4(0.f, 0.f, 0.f, 0.f);
  float s = 0.f, s2 = 0.f;
#pragma unroll
  for (int i = 0; i < 4; ++i) {
    s += v[i].x + v[i].y + v[i].z + v[i].w;
    s2 = fmaf(v[i].x, v[i].x, s2); s2 = fmaf(v[i].y, v[i].y, s2);
    s2 = fmaf(v[i].z, v[i].z, s2); s2 = fmaf(v[i].w, v[i].w, s2);
  }
  scr[r * 8 + j] = s;
  scr[256 + r * 8 + j] = s2;
  __syncthreads();
  if (tid < 32) {
    float ss = 0.f, q2 = 0.f;
#pragma unroll
    for (int i = 0; i < 8; ++i) { ss += scr[tid * 8 + i]; q2 += scr[256 + tid * 8 + i]; }
    float mn = ss * (1.f / 128.f);
    float vr = fmaf(-mn, mn, q2 * (1.f / 128.f));
    scr[512 + tid] = mn;
    scr[544 + tid] = rsqrtf(vr + 1e-5f);
  }
  __syncthreads();
  if (!valid) return;
  float mn = scr[512 + r], rs = scr[544 + r];
  short8 o[2];
#pragma unroll
  for (int i = 0; i < 4; ++i) {
    int c0 = j * 16 + i * 4;
    float4 gg = *(const float4*)(g + c0);
    float4 bb = *(const float4*)(be + c0);
    float* vf = (float*)&v[i];
    float* gf = (float*)&gg;
    float* bf = (float*)&bb;
#pragma unroll
    for (int e = 0; e < 4; ++e)
      o[i >> 1][(i & 1) * 4 + e] = f2bf(fmaf((vf[e] - mn) * rs, gf[e], bf[e]));
  }
  *(short8*)(out + (size_t)rg * 128 + j * 16) = o[0];
  *(short8*)(out + (size_t)rg * 128 + j * 16 + 8) = o[1];
}

// ---------------- kernel 2: fully-fused per-node block (MFMA) --------------
// 1 node/block, ~33KB LDS, __launch_bounds__(256,3) (R3-proven spill-free).
// Node FFN is FUSED: out_node[base] is complete at S6, so its LN stats ride
// S7's barriers, and two M=1 MFMA GEMMs (A row 0 = x, rows 1-15 zeroed) ride
// S8/S9 using the dedicated 768B `ffn` LDS region. Kills the 4th kernel +
// its kernel-boundary serialization + the out_node HBM round trip.
// Regions (8KB each): R0: EA->MS->CX->EHN ; R1: NB->QH(+P)->R ;
// R2: EH->KH(+P)->{LNscr,x}->HID.lo ; R3: NH->VT->HID.hi ; ffn: xb+hid.
__global__ __launch_bounds__(256, 3) void egab_main(
    const float* __restrict__ nf, const float* __restrict__ ef,
    const float* __restrict__ ea, const int* __restrict__ nlist,
    const int* __restrict__ nvalid,
    const float* __restrict__ b_edge, const float* __restrict__ b_node,
    const float* __restrict__ b_msg, const float* __restrict__ b_qkv,
    const float* __restrict__ b_out, const float* __restrict__ g_fe,
    const float* __restrict__ be_fe, const float* __restrict__ be1,
    const float* __restrict__ be2, const float* __restrict__ g_fn,
    const float* __restrict__ be_fn, const float* __restrict__ bn1,
    const float* __restrict__ bn2,
    const short* __restrict__ WtE, const short* __restrict__ WtN,
    const short* __restrict__ WtM, const short* __restrict__ WtQ,
    const short* __restrict__ WtO, const short* __restrict__ WtE1,
    const short* __restrict__ WtE2, const short* __restrict__ WtN1,
    const short* __restrict__ WtN2, const short* __restrict__ nh_bf,
    float* __restrict__ out_node, float* __restrict__ out_edge) {
  __shared__ short lds[16384 + 384];
  short* R0 = lds;
  short* R1 = lds + 4096;
  short* R2 = lds + 8192;
  short* R3 = lds + 12288;
  short* ffn = lds + 16384;  // xb[128] + hid[256]

  const int tid = threadIdx.x;
  const int w = tid >> 6;
  const int lane = tid & 63;
  const int lm = lane & 15, lq = lane >> 4;
  const int base = blockIdx.x;      // 1 node per block
  const int n0 = w * 32;            // wave col slice for Nout=128 GEMMs
  const short8 zz8 = {0, 0, 0, 0, 0, 0, 0, 0};

  // node-FFN residual x, kept in registers from S6 to the final GEMM2 epi
  float xres[2];

  // ---- prefetch ef (S6) + nf (residual) into registers: HBM latency hides
  //      under S2-S5 compute ----
  float efr[2][2][4];
  float nfr[2];
#pragma unroll
  for (int mt = 0; mt < 2; ++mt)
#pragma unroll
    for (int nt = 0; nt < 2; ++nt)
#pragma unroll
      for (int rr = 0; rr < 4; ++rr)
        efr[mt][nt][rr] =
            ef[((size_t)base * KNBR + mt * 16 + lq * 4 + rr) * 128 + n0 +
               nt * 16 + lm];
#pragma unroll
  for (int nt = 0; nt < 2; ++nt)
    nfr[nt] = nf[(size_t)base * 128 + n0 + nt * 16 + lm];

  // ---- S1: edge_attr -> EA(R0) bf16 swizzled; gather neighbors -> NB(R1) ----
  {
    const float* eap = ea + (size_t)base * 4096;
    int r = tid >> 3;
    int sg = tid & 7;
#pragma unroll
    for (int j = 0; j < 2; ++j) {
      int ch = sg * 2 + j;
      float4 fa = ((const float4*)eap)[r * 32 + ch * 2];
      float4 fb = ((const float4*)eap)[r * 32 + ch * 2 + 1];
      short8 v = {f2bf(fa.x), f2bf(fa.y), f2bf(fa.z), f2bf(fa.w),
                  f2bf(fb.x), f2bf(fb.y), f2bf(fb.z), f2bf(fb.w)};
      *(short8*)(R0 + r * 128 + ((ch ^ (r & 7)) << 3)) = v;
    }
    int idx = nlist[base * KNBR + r];
    const short* srow = nh_bf + (size_t)idx * 128;
#pragma unroll
    for (int j = 0; j < 2; ++j) {
      int ch = sg * 2 + j;
      short8 v = *(const short8*)(srow + ch * 8);
      *(short8*)(R1 + r * 128 + ((ch ^ (r & 7)) << 3)) = v;
    }
  }
  __syncthreads();

  // ---- S2: edge_hidden = gelu(EA @ WtE) -> EH(R2);
  //          node_hid = gelu([center|NB] @ WtN) -> NH(R3) ----
  wgemm_t<2, 2, 4>(
      [&](int r, int k, int q) { return ld_sw128(R0, r, k * 4 + q); },
      WtE + (size_t)n0 * 128,
      [&](int mt, int nt, f32x4 acc) {
        int colb = n0 + nt * 16 + lq * 4;
        float4 bb = *(const float4*)(b_edge + colb);
        st_sw128_v4(R2, mt * 16 + lm, colb, pack_gelu4(acc, bb));
      });
  wgemm_t<2, 2, 8>(
      [&](int r, int k, int q) {
        if (k < 4)  // center row (broadcast, one per node) from global bf16
          return *(const short8*)(nh_bf + (size_t)base * 128 + k * 32 + q * 8);
        return ld_sw128(R1, r, (k - 4) * 4 + q);
      },
      WtN + (size_t)n0 * 256,
      [&](int mt, int nt, f32x4 acc) {
        int colb = n0 + nt * 16 + lq * 4;
        float4 bb = *(const float4*)(b_node + colb);
        st_sw128_v4(R3, mt * 16 + lm, colb, pack_gelu4(acc, bb));
      });
  __syncthreads();

  // ---- S3: msg = gelu([EH|NH] @ WtM) -> MS(R0) ----
  wgemm_t<2, 2, 8>(
      [&](int r, int k, int q) {
        if (k < 4) return ld_sw128(R2, r, k * 4 + q);
        return ld_sw128(R3, r, (k - 4) * 4 + q);
      },
      WtM + (size_t)n0 * 256,
      [&](int mt, int nt, f32x4 acc) {
        int colb = n0 + nt * 16 + lq * 4;
        float4 bb = *(const float4*)(b_msg + colb);
        st_sw128_v4(R0, mt * 16 + lm, colb, pack_gelu4(acc, bb));
      });
  __syncthreads();

  // ---- S4: qkv = MS @ WtQ ; q -> QH(R1) [8][32][16], k -> KH(R2),
  //          v -> VT(R3) [128 rows=v-col][32 m] chunk-swizzled ----
  {
    const int q0 = w * 96;
    wgemm<2, 6, 4>(
        [&](int r, int k, int q) { return ld_sw128(R0, r, k * 4 + q); },
        WtQ + (size_t)q0 * 128,
        [&](int mt, int nt, f32x4 acc) {
          int c = q0 + nt * 16;  // tile-uniform global col base
          float bb = b_qkv[c + lm];
          int m = mt * 16 + lq * 4;
          if (c < 256) {
            short* dst = (c < 128 ? R1 + ((c >> 4) * 32) * 16
                                  : R2 + (((c - 128) >> 4) * 32) * 16);
#pragma unroll
            for (int rr = 0; rr < 4; ++rr)
              dst[(m + rr) * 16 + lm] = f2bf(acc[rr] + bb);
          } else {
            int rv = (c - 256) + lm;  // v column 0..127 -> VT row
            short4v pv;
#pragma unroll
            for (int rr = 0; rr < 4; ++rr) pv[rr] = f2bf(acc[rr] + bb);
            int chv = m >> 3;
            *(short4v*)(R3 + rv * 32 + ((chv ^ (rv & 3)) << 3) + (m & 7)) = pv;
          }
        });
  }
  __syncthreads();

  // ---- S5: 8-head attention, one head instance per wave-iter ----
  {
    const f32x4 z4 = {0.f, 0.f, 0.f, 0.f};
    const int nvv = nvalid[base];
#pragma unroll
    for (int it = 0; it < 2; ++it) {
      int h = (it << 2) | w;
      short* qh = R1 + h * 512;
      short* kh = R2 + h * 512;
      short8 bk[2];
#pragma unroll
      for (int nt = 0; nt < 2; ++nt)
        bk[nt] = (lq < 2) ? *(const short8*)(kh + (nt * 16 + lm) * 16 + lq * 8) : zz8;
      float sc[2][2][4];
#pragma unroll
      for (int mt = 0; mt < 2; ++mt) {
        short8 aq = (lq < 2) ? *(const short8*)(qh + (mt * 16 + lm) * 16 + lq * 8) : zz8;
#pragma unroll
        for (int nt = 0; nt < 2; ++nt) {
          f32x4 s = mfma16(aq, bk[nt], z4);
#pragma unroll
          for (int rr = 0; rr < 4; ++rr) {
            float x = s[rr] * 0.25f;
            if (nt * 16 + lm >= nvv) x = -1e9f;
            sc[mt][nt][rr] = x;
          }
        }
      }
      // softmax per row (row = mt*16 + lq*4 + rr, cols distributed over lm)
#pragma unroll
      for (int mt = 0; mt < 2; ++mt)
#pragma unroll
        for (int rr = 0; rr < 4; ++rr) {
          float x0 = sc[mt][0][rr], x1 = sc[mt][1][rr];
          float mx = fmaxf(x0, x1);
          mx = fmaxf(mx, __shfl_xor(mx, 1, 16));
          mx = fmaxf(mx, __shfl_xor(mx, 2, 16));
          mx = fmaxf(mx, __shfl_xor(mx, 4, 16));
          mx = fmaxf(mx, __shfl_xor(mx, 8, 16));
          float e0 = __expf(x0 - mx), e1 = __expf(x1 - mx);
          float sm = e0 + e1;
          sm += __shfl_xor(sm, 1, 16);
          sm += __shfl_xor(sm, 2, 16);
          sm += __shfl_xor(sm, 4, 16);
          sm += __shfl_xor(sm, 8, 16);
          float ri = 1.f / sm;
          int row = mt * 16 + lq * 4 + rr;
          qh[row * 16 + lm] = f2bf(e0 * ri);  // P cols 0-15
          kh[row * 16 + lm] = f2bf(e1 * ri);  // P cols 16-31
        }
      // PV: A = P (K=32), B = VT head rows -> ctx into CX(R0)
#pragma unroll
      for (int mt = 0; mt < 2; ++mt) {
        const short* psrc = (lq < 2) ? qh : kh;
        short8 pa = *(const short8*)(psrc + (mt * 16 + lm) * 16 + (lq & 1) * 8);
        int rv = h * 16 + lm;
        short8 vb = *(const short8*)(R3 + rv * 32 + ((lq ^ (rv & 3)) << 3));
        f32x4 c = mfma16(pa, vb, z4);
#pragma unroll
        for (int rr = 0; rr < 4; ++rr)
          st_sw128(R0, mt * 16 + lq * 4 + rr, h * 16 + lm, f2bf(c[rr]));
      }
    }
  }
  __syncthreads();

  // ---- S6: edge_out = CX @ WtO + b_out; R(R1) = edge_out + ef (bf16);
  //          node_res x = sum_{k<nv} edge_out + nf -> registers + LDS ----
  {
    int nv = nvalid[base];
    float nsum[2] = {0.f, 0.f};
    wgemm<2, 2, 4>(
        [&](int r, int k, int q) { return ld_sw128(R0, r, k * 4 + q); },
        WtO + (size_t)n0 * 128,
        [&](int mt, int nt, f32x4 acc) {
          int col = n0 + nt * 16 + lm;
          float bb = b_out[col];
#pragma unroll
          for (int rr = 0; rr < 4; ++rr) {
            int kk = mt * 16 + lq * 4 + rr;
            float eo = acc[rr] + bb;
            if (kk < nv) nsum[nt] += eo;
            st_sw128(R1, kk, col, f2bf(eo + efr[mt][nt][rr]));
          }
        });
    float* xf = (float*)R2;  // x stash at float idx 1024..1151 (KH is dead)
#pragma unroll
    for (int nt = 0; nt < 2; ++nt) {
      float v = nsum[nt];
      v += __shfl_xor(v, 16, 64);
      v += __shfl_xor(v, 32, 64);
      xres[nt] = v + nfr[nt];
      if (lq == 0) xf[1024 + n0 + nt * 16 + lm] = xres[nt];
    }
  }
  __syncthreads();

  // ---- S7: EHN(R0) = LayerNorm_fe(R); FFN-LN of x rides the same barriers ----
  {
    float* scr = (float*)R2;   // floats 0..~640 scratch; x at 1024..1151
    int r = tid >> 3, sg = tid & 7;
    short8 xv[2];
    float s = 0.f, s2 = 0.f;
#pragma unroll
    for (int j = 0; j < 2; ++j) {
      int ch = sg * 2 + j;
      xv[j] = *(const short8*)(R1 + r * 128 + ((ch ^ (r & 7)) << 3));
#pragma unroll
      for (int e = 0; e < 8; ++e) {
        float x = bf2f(xv[j][e]);
        s += x;
        s2 = fmaf(x, x, s2);
      }
    }
    scr[r * 8 + sg] = s;
    scr[256 + r * 8 + sg] = s2;
    // FFN-LN partials (x written before the S6->S7 barrier)
    if (tid < 32) {
      float4 x4 = *(const float4*)(scr + 1024 + tid * 4);
      scr[832 + tid] = x4.x + x4.y + x4.z + x4.w;
      scr[864 + tid] = fmaf(x4.x, x4.x, fmaf(x4.y, x4.y,
                       fmaf(x4.z, x4.z, x4.w * x4.w)));
    }
    __syncthreads();
    if (tid < 32) {
      float ss = 0.f, q2 = 0.f;
#pragma unroll
      for (int i = 0; i < 8; ++i) { ss += scr[tid * 8 + i]; q2 += scr[256 + tid * 8 + i]; }
      float mn = ss * (1.f / 128.f);
      float vr = fmaf(-mn, mn, q2 * (1.f / 128.f));
      scr[512 + tid * 2] = mn;
      scr[512 + tid * 2 + 1] = rsqrtf(vr + 1e-5f);
    } else if (tid == 64) {
      float ss = 0.f, q2 = 0.f;
#pragma unroll
      for (int i = 0; i < 32; ++i) { ss += scr[832 + i]; q2 += scr[864 + i]; }
      float mn = ss * (1.f / 128.f);
      float vr = fmaf(-mn, mn, q2 * (1.f / 128.f));
      scr[896] = mn;
      scr[897] = rsqrtf(vr + 1e-5f);
    }
    __syncthreads();
    float mn = scr[512 + r * 2], rs = scr[512 + r * 2 + 1];
#pragma unroll
    for (int j = 0; j < 2; ++j) {
      int ch = sg * 2 + j;
      int c0 = ch * 8;
      float4 g0 = *(const float4*)(g_fe + c0);
      float4 g1 = *(const float4*)(g_fe + c0 + 4);
      float4 b0 = *(const float4*)(be_fe + c0);
      float4 b1 = *(const float4*)(be_fe + c0 + 4);
      const float* gp0 = (const float*)&g0;
      const float* gp1 = (const float*)&g1;
      const float* bp0 = (const float*)&b0;
      const float* bp1 = (const float*)&b1;
      short8 ov;
#pragma unroll
      for (int e = 0; e < 4; ++e) {
        ov[e] = f2bf(fmaf((bf2f(xv[j][e]) - mn) * rs, gp0[e], bp0[e]));
        ov[4 + e] = f2bf(fmaf((bf2f(xv[j][4 + e]) - mn) * rs, gp1[e], bp1[e]));
      }
      *(short8*)(R0 + r * 128 + ((ch ^ (r & 7)) << 3)) = ov;
    }
    // FFN xb = LN_fn(x) in bf16 -> ffn[0..127]
    if (tid < 128) {
      float mx = scr[896], rx = scr[897];
      ffn[tid] = f2bf(fmaf((scr[1024 + tid] - mx) * rx, g_fn[tid], be_fn[tid]));
    }
  }
  __syncthreads();

  // ---- S8: HID(R2..R3) = gelu(EHN @ WtE1 + be1); FFN GEMM1 alongside ----
  {
    const int f0 = w * 64;
    wgemm_t<2, 4, 4>(
        [&](int r, int k, int q) { return ld_sw128(R0, r, k * 4 + q); },
        WtE1 + (size_t)f0 * 128,
        [&](int mt, int nt, f32x4 acc) {
          int colb = f0 + nt * 16 + lq * 4;
          float4 bb = *(const float4*)(be1 + colb);
          st_sw256_v4(R2, mt * 16 + lm, colb, pack_gelu4(acc, bb));
        });
    // FFN GEMM1: hid = gelu(x @ Wn1 + bn1), M=1 (A row 0 = xb, rows 1-15 = 0)
    wgemm<1, 4, 4>(
        [&](int r, int k, int q) {
          short8 av = *(const short8*)(ffn + k * 32 + q * 8);  // broadcast
          return (lm == 0) ? av : zz8;
        },
        WtN1 + (size_t)f0 * 128,
        [&](int mt, int nt, f32x4 acc) {
          (void)mt;
          if (lq == 0) {
            int col = f0 + nt * 16 + lm;
            ffn[128 + col] = f2bf(gelu_f(acc[0] + bn1[col]));
          }
        });
  }
  __syncthreads();

  // ---- S9: out_edge = R + HID @ WtE2 + be2; FFN GEMM2 -> out_node ----
  wgemm<2, 2, 8>(
      [&](int r, int k, int q) { return ld_sw256(R2, r, k * 4 + q); },
      WtE2 + (size_t)n0 * 256,
      [&](int mt, int nt, f32x4 acc) {
        int col = n0 + nt * 16 + lm;
        float bb = be2[col];
#pragma unroll
        for (int rr = 0; rr < 4; ++rr) {
          int m = mt * 16 + lq * 4 + rr;
          float rv = bf2f(R1[m * 128 + ((((col >> 3) ^ (m & 7))) << 3) + (col & 7)]);
          out_edge[((size_t)base * KNBR + m) * 128 + col] = rv + acc[rr] + bb;
        }
      });
  // FFN GEMM2: out_node = x + hid @ Wn2 + bn2, M=1
  wgemm<1, 2, 8>(
      [&](int r, int k, int q) {
        short8 av = *(const short8*)(ffn + 128 + k * 32 + q * 8);  // broadcast
        return (lm == 0) ? av : zz8;
      },
      WtN2 + (size_t)n0 * 256,
      [&](int mt, int nt, f32x4 acc) {
        (void)mt;
        if (lq == 0) {
          int col = n0 + nt * 16 + lm;
          out_node[(size_t)base * 128 + col] = xres[nt] + acc[0] + bn2[col];
        }
      });
}

// ---------------- launch ----------------
extern "C" void kernel_launch(void* const* d_in, const int* in_sizes, int n_in,
                              void* d_out, int out_size, void* d_ws,
                              size_t ws_size, hipStream_t stream) {
  (void)in_sizes; (void)n_in; (void)out_size; (void)ws_size;
  const float* nf = (const float*)d_in[0];
  const float* ef = (const float*)d_in[1];
  const float* ea = (const float*)d_in[2];
  const int* nlist = (const int*)d_in[3];
  const int* nvalid = (const int*)d_in[4];
  const float* W_edge = (const float*)d_in[5];
  const float* b_edge = (const float*)d_in[6];
  const float* W_node = (const float*)d_in[7];
  const float* b_node = (const float*)d_in[8];
  const float* W_msg = (const float*)d_in[9];
  const float* b_msg = (const float*)d_in[10];
  const float* W_qkv = (const float*)d_in[11];
  const float* b_qkv = (const float*)d_in[12];
  const float* W_out = (const float*)d_in[13];
  const float* b_out = (const float*)d_in[14];
  const float* g_attn = (const float*)d_in[15];
  const float* be_attn = (const float*)d_in[16];
  const float* g_fn = (const float*)d_in[17];
  const float* be_fn = (const float*)d_in[18];
  const float* g_fe = (const float*)d_in[19];
  const float* be_fe = (const float*)d_in[20];
  const float* Wn1 = (const float*)d_in[21];
  const float* bn1 = (const float*)d_in[22];
  const float* Wn2 = (const float*)d_in[23];
  const float* bn2 = (const float*)d_in[24];
  const float* We1 = (const float*)d_in[25];
  const float* be1 = (const float*)d_in[26];
  const float* We2 = (const float*)d_in[27];
  const float* be2 = (const float*)d_in[28];

  short* ws0 = (short*)d_ws;           // node_hidden bf16 [N][128]
  short* wsW = ws0 + 1280000;          // transposed bf16 weights, 278528 elems
  short* WtE = wsW;
  short* WtN = wsW + 16384;
  short* WtM = wsW + 49152;
  short* WtQ = wsW + 81920;
  short* WtO = wsW + 131072;
  short* WtE1 = wsW + 147456;
  short* WtE2 = wsW + 180224;
  short* WtN1 = wsW + 212992;
  short* WtN2 = wsW + 245760;

  float* out_node = (float*)d_out;
  float* out_edge = out_node + (size_t)N_NODES * 128;

  WSrc wsrc;
  wsrc.p[0] = W_edge; wsrc.p[1] = W_node; wsrc.p[2] = W_msg;
  wsrc.p[3] = W_qkv;  wsrc.p[4] = W_out;  wsrc.p[5] = We1;
  wsrc.p[6] = We2;    wsrc.p[7] = Wn1;    wsrc.p[8] = Wn2;

  wprep_kernel<<<1088, 256, 0, stream>>>(wsrc, wsW);
  ln_in_kernel<<<(N_NODES + 31) / 32, 256, 0, stream>>>(nf, g_attn, be_attn, ws0);
  egab_main<<<N_NODES, 256, 0, stream>>>(
      nf, ef, ea, nlist, nvalid, b_edge, b_node, b_msg, b_qkv, b_out, g_fe,
      be_fe, be1, be2, g_fn, be_fn, bn1, bn2, WtE, WtN, WtM, WtQ, WtO, WtE1,
      WtE2, WtN1, WtN2, ws0, out_node, out_edge);
}

// Round 8
// 892.598 us; speedup vs baseline: 1.1456x; 1.1456x over previous
//
#include <hip/hip_runtime.h>
#include <hip/hip_bf16.h>
#include <cstddef>

#define N_NODES 10000
#define KNBR 32
#define HDIM 128
#define NHEADS 8

using short8 = __attribute__((ext_vector_type(8))) short;
using short4v = __attribute__((ext_vector_type(4))) short;
using f32x4 = __attribute__((ext_vector_type(4))) float;

__device__ __forceinline__ f32x4 mfma16(short8 a, short8 b, f32x4 c) {
  return __builtin_amdgcn_mfma_f32_16x16x32_bf16(a, b, c, 0, 0, 0);
}

// HW bf16 convert (RNE)
__device__ __forceinline__ short f2bf(float f) {
  __hip_bfloat16 h = __float2bfloat16(f);
  return __builtin_bit_cast(short, h);
}
__device__ __forceinline__ float bf2f(short s) {
  unsigned u = ((unsigned)(unsigned short)s) << 16;
  return __builtin_bit_cast(float, u);
}

// tanh-approx gelu == x * sigmoid(1.59577x + 0.0713548x^3), exp folded into
// exp2 + rcp (~7 VALU ops vs ~15 for the divide form). Verified R7 (absmax ok).
__device__ __forceinline__ float gelu_f(float x) {
  float u = x * fmaf(x * x, -0.1029432f, -2.3022077f);
  return x * __builtin_amdgcn_rcpf(1.0f + __builtin_amdgcn_exp2f(u));
}

__device__ __forceinline__ short4v pack4f(float a, float b, float c, float d) {
  short4v v; v[0] = f2bf(a); v[1] = f2bf(b); v[2] = f2bf(c); v[3] = f2bf(d);
  return v;
}
__device__ __forceinline__ short4v pack_gelu4(f32x4 acc, float4 bb) {
  return pack4f(gelu_f(acc[0] + bb.x), gelu_f(acc[1] + bb.y),
                gelu_f(acc[2] + bb.z), gelu_f(acc[3] + bb.w));
}

// Swizzled LDS tiles: row-major [rows][128 or 256] bf16, 16B chunk c of row r
// stored at physical chunk (c ^ (r&7)). Conflict-free A-frag ds_read_b128.
__device__ __forceinline__ short8 ld_sw128(const short* b, int r, int ch) {
  return *(const short8*)(b + r * 128 + (((ch ^ (r & 7))) << 3));
}
__device__ __forceinline__ short8 ld_sw256(const short* b, int r, int ch) {
  return *(const short8*)(b + r * 256 + (((ch ^ (r & 7))) << 3));
}
__device__ __forceinline__ void st_sw128(short* b, int r, int col, short v) {
  b[r * 128 + ((((col >> 3) ^ (r & 7))) << 3) + (col & 7)] = v;
}
// b64 store of 4 consecutive cols (colb aligned to 4) of row r
__device__ __forceinline__ void st_sw128_v4(short* b, int r, int colb, short4v v) {
  *(short4v*)(b + r * 128 + ((((colb >> 3) ^ (r & 7))) << 3) + (colb & 7)) = v;
}
__device__ __forceinline__ void st_sw256_v4(short* b, int r, int colb, short4v v) {
  *(short4v*)(b + r * 256 + ((((colb >> 3) ^ (r & 7))) << 3) + (colb & 7)) = v;
}

// ---- Per-wave MFMA GEMM building blocks -----------------------------------
// A-preload (R3-proven ILP) with KS<=4. KS=8 GEMMs are SPLIT into two KS=4
// passes with a register-carried acc[MT][NT] (16 regs for 2x2): same A-reads,
// same B-loads, same MFMA count and intra-nt ILP, but peak register pressure
// drops from ~84-100 to ~75-85 -> fits the 128-reg slice of
// __launch_bounds__(256,4) without R4's spills or R5's k-outer ILP loss.

// Single-shot form (KS<=4), transient acc, epi per (mt,nt).
// Normal: epi acc[rr] = C[row = mt*16 + lq*4 + rr][col = nt*16 + lm].
template <int MT, int NT, int KS, typename ALoad, typename Epi>
__device__ __forceinline__ void wgemm(ALoad aload, const short* __restrict__ Bt,
                                      Epi epi) {
  const int lane = threadIdx.x & 63;
  const int lm = lane & 15, lq = lane >> 4;
  short8 a[MT][KS];
#pragma unroll
  for (int mt = 0; mt < MT; ++mt)
#pragma unroll
    for (int k = 0; k < KS; ++k) a[mt][k] = aload(mt * 16 + lm, k, lq);
#pragma unroll
  for (int nt = 0; nt < NT; ++nt) {
    short8 b[KS];
#pragma unroll
    for (int k = 0; k < KS; ++k)
      b[k] = *(const short8*)(Bt + (nt * 16 + lm) * (KS * 32) + k * 32 + lq * 8);
#pragma unroll
    for (int mt = 0; mt < MT; ++mt) {
      f32x4 acc = {0.f, 0.f, 0.f, 0.f};
#pragma unroll
      for (int k = 0; k < KS; ++k) acc = mfma16(a[mt][k], b[k], acc);
      epi(mt, nt, acc);
    }
  }
}

// Transposed single-shot (operands swapped; legal, verified R5):
// epi acc[rr] = C[row = mt*16 + lm][col = nt*16 + lq*4 + rr].
template <int MT, int NT, int KS, typename ALoad, typename Epi>
__device__ __forceinline__ void wgemm_t(ALoad aload, const short* __restrict__ Bt,
                                        Epi epi) {
  const int lane = threadIdx.x & 63;
  const int lm = lane & 15, lq = lane >> 4;
  short8 a[MT][KS];
#pragma unroll
  for (int mt = 0; mt < MT; ++mt)
#pragma unroll
    for (int k = 0; k < KS; ++k) a[mt][k] = aload(mt * 16 + lm, k, lq);
#pragma unroll
  for (int nt = 0; nt < NT; ++nt) {
    short8 b[KS];
#pragma unroll
    for (int k = 0; k < KS; ++k)
      b[k] = *(const short8*)(Bt + (nt * 16 + lm) * (KS * 32) + k * 32 + lq * 8);
#pragma unroll
    for (int mt = 0; mt < MT; ++mt) {
      f32x4 acc = {0.f, 0.f, 0.f, 0.f};
#pragma unroll
      for (int k = 0; k < KS; ++k) acc = mfma16(b[k], a[mt][k], acc);
      epi(mt, nt, acc);
    }
  }
}

// Split-K pass: accumulates into caller's acc. brs = B row stride (elements),
// so a KS=8 weight layout (stride 256) can be consumed in two KS=4 passes
// (second pass: Bt += 128).
template <int MT, int NT, int KS, typename ALoad>
__device__ __forceinline__ void wgemm_pass(ALoad aload,
                                           const short* __restrict__ Bt,
                                           int brs, f32x4 (&acc)[MT][NT]) {
  const int lane = threadIdx.x & 63;
  const int lm = lane & 15, lq = lane >> 4;
  short8 a[MT][KS];
#pragma unroll
  for (int mt = 0; mt < MT; ++mt)
#pragma unroll
    for (int k = 0; k < KS; ++k) a[mt][k] = aload(mt * 16 + lm, k, lq);
#pragma unroll
  for (int nt = 0; nt < NT; ++nt) {
    short8 b[KS];
#pragma unroll
    for (int k = 0; k < KS; ++k)
      b[k] = *(const short8*)(Bt + (nt * 16 + lm) * brs + k * 32 + lq * 8);
#pragma unroll
    for (int mt = 0; mt < MT; ++mt)
#pragma unroll
      for (int k = 0; k < KS; ++k)
        acc[mt][nt] = mfma16(a[mt][k], b[k], acc[mt][nt]);
  }
}

template <int MT, int NT, int KS, typename ALoad>
__device__ __forceinline__ void wgemm_t_pass(ALoad aload,
                                             const short* __restrict__ Bt,
                                             int brs, f32x4 (&acc)[MT][NT]) {
  const int lane = threadIdx.x & 63;
  const int lm = lane & 15, lq = lane >> 4;
  short8 a[MT][KS];
#pragma unroll
  for (int mt = 0; mt < MT; ++mt)
#pragma unroll
    for (int k = 0; k < KS; ++k) a[mt][k] = aload(mt * 16 + lm, k, lq);
#pragma unroll
  for (int nt = 0; nt < NT; ++nt) {
    short8 b[KS];
#pragma unroll
    for (int k = 0; k < KS; ++k)
      b[k] = *(const short8*)(Bt + (nt * 16 + lm) * brs + k * 32 + lq * 8);
#pragma unroll
    for (int mt = 0; mt < MT; ++mt)
#pragma unroll
      for (int k = 0; k < KS; ++k)
        acc[mt][nt] = mfma16(b[k], a[mt][k], acc[mt][nt]);
  }
}

// ---------------- kernel 0: weights -> bf16 transposed in ws ----------------
struct WSrc { const float* p[9]; };

__global__ void wprep_kernel(WSrc ws, short* __restrict__ dst) {
  const int cum[10] = {0, 16384, 49152, 81920, 131072, 147456, 180224, 212992, 245760, 278528};
  const int Ks[9] = {128, 256, 256, 128, 128, 128, 256, 128, 256};
  const int Ns[9] = {128, 128, 128, 384, 128, 256, 128, 256, 128};
  int eg = blockIdx.x * 256 + threadIdx.x;
  int id = 0;
#pragma unroll
  for (int i = 0; i < 8; ++i) id += (eg >= cum[i + 1]) ? 1 : 0;
  int e = eg - cum[id];
  int K = Ks[id];
  int n = (K == 128) ? (e >> 7) : (e >> 8);
  int k = e - n * K;
  dst[eg] = f2bf(ws.p[id][k * Ns[id] + n]);
}

// ---------------- kernel 1: LN(node_features) -> bf16 ws0 ----------------
__global__ __launch_bounds__(256) void ln_in_kernel(
    const float* __restrict__ in, const float* __restrict__ g,
    const float* __restrict__ be, short* __restrict__ out) {
  __shared__ float scr[32 * 8 * 2 + 64];
  const int tid = threadIdx.x;
  const int r = tid >> 3, j = tid & 7;
  const int base = blockIdx.x * 32;
  const int rg = base + r;
  const bool valid = rg < N_NODES;
  float4 v[4];
#pragma unroll
  for (int i = 0; i < 4; ++i)
    v[i] = valid ? ((const float4*)(in + (size_t)rg * 128 + j * 16))[i]
                 : make_float4(0.f, 0.f, 0.f, 0.f);
  float s = 0.f, s2 = 0.f;
#pragma unroll
  for (int i = 0; i < 4; ++i) {
    s += v[i].x + v[i].y + v[i].z + v[i].w;
    s2 = fmaf(v[i].x, v[i].x, s2); s2 = fmaf(v[i].y, v[i].y, s2);
    s2 = fmaf(v[i].z, v[i].z, s2); s2 = fmaf(v[i].w, v[i].w, s2);
  }
  scr[r * 8 + j] = s;
  scr[256 + r * 8 + j] = s2;
  __syncthreads();
  if (tid < 32) {
    float ss = 0.f, q2 = 0.f;
#pragma unroll
    for (int i = 0; i < 8; ++i) { ss += scr[tid * 8 + i]; q2 += scr[256 + tid * 8 + i]; }
    float mn = ss * (1.f / 128.f);
    float vr = fmaf(-mn, mn, q2 * (1.f / 128.f));
    scr[512 + tid] = mn;
    scr[544 + tid] = rsqrtf(vr + 1e-5f);
  }
  __syncthreads();
  if (!valid) return;
  float mn = scr[512 + r], rs = scr[544 + r];
  short8 o[2];
#pragma unroll
  for (int i = 0; i < 4; ++i) {
    int c0 = j * 16 + i * 4;
    float4 gg = *(const float4*)(g + c0);
    float4 bb = *(const float4*)(be + c0);
    float* vf = (float*)&v[i];
    float* gf = (float*)&gg;
    float* bf = (float*)&bb;
#pragma unroll
    for (int e = 0; e < 4; ++e)
      o[i >> 1][(i & 1) * 4 + e] = f2bf(fmaf((vf[e] - mn) * rs, gf[e], bf[e]));
  }
  *(short8*)(out + (size_t)rg * 128 + j * 16) = o[0];
  *(short8*)(out + (size_t)rg * 128 + j * 16 + 8) = o[1];
}

// ---------------- kernel 2: fused per-node block (MFMA), 1 node/block -------
// 32KB LDS, __launch_bounds__(256,4): KS=8 GEMMs split into two KS=4 passes
// (register-carried acc) so peak pressure fits the 128-reg slice -> 4
// waves/SIMD spill-free. Spill tripwire: WRITE_SIZE must stay ~165MB.
// Regions (8KB each, [32][128] bf16): lifetime-aliased:
// R0: EA -> MS -> CX -> EHN ; R1: NB -> QH(+P) -> R(res bf16)
// R2: EH -> KH(+P) -> LNscr -> HID.lo ; R3: NH -> VT -> HID.hi
__global__ __launch_bounds__(256, 4) void egab_main(
    const float* __restrict__ nf, const float* __restrict__ ef,
    const float* __restrict__ ea, const int* __restrict__ nlist,
    const int* __restrict__ nvalid,
    const float* __restrict__ b_edge, const float* __restrict__ b_node,
    const float* __restrict__ b_msg, const float* __restrict__ b_qkv,
    const float* __restrict__ b_out, const float* __restrict__ g_fe,
    const float* __restrict__ be_fe, const float* __restrict__ be1,
    const float* __restrict__ be2,
    const short* __restrict__ WtE, const short* __restrict__ WtN,
    const short* __restrict__ WtM, const short* __restrict__ WtQ,
    const short* __restrict__ WtO, const short* __restrict__ WtE1,
    const short* __restrict__ WtE2, const short* __restrict__ nh_bf,
    float* __restrict__ out_node, float* __restrict__ out_edge) {
  __shared__ short lds[16384];
  short* R0 = lds;
  short* R1 = lds + 4096;
  short* R2 = lds + 8192;
  short* R3 = lds + 12288;

  const int tid = threadIdx.x;
  const int w = tid >> 6;
  const int lane = tid & 63;
  const int lm = lane & 15, lq = lane >> 4;
  const int base = blockIdx.x;      // 1 node per block
  const int n0 = w * 32;            // wave col slice for Nout=128 GEMMs

  // ---- S1: edge_attr -> EA(R0) bf16 swizzled; gather neighbors -> NB(R1) ----
  {
    const float* eap = ea + (size_t)base * 4096;
    int r = tid >> 3;
    int sg = tid & 7;
#pragma unroll
    for (int j = 0; j < 2; ++j) {
      int ch = sg * 2 + j;
      float4 fa = ((const float4*)eap)[r * 32 + ch * 2];
      float4 fb = ((const float4*)eap)[r * 32 + ch * 2 + 1];
      short8 v = {f2bf(fa.x), f2bf(fa.y), f2bf(fa.z), f2bf(fa.w),
                  f2bf(fb.x), f2bf(fb.y), f2bf(fb.z), f2bf(fb.w)};
      *(short8*)(R0 + r * 128 + ((ch ^ (r & 7)) << 3)) = v;
    }
    int idx = nlist[base * KNBR + r];
    const short* srow = nh_bf + (size_t)idx * 128;
#pragma unroll
    for (int j = 0; j < 2; ++j) {
      int ch = sg * 2 + j;
      short8 v = *(const short8*)(srow + ch * 8);
      *(short8*)(R1 + r * 128 + ((ch ^ (r & 7)) << 3)) = v;
    }
  }
  __syncthreads();

  // ---- S2: edge_hidden = gelu(EA @ WtE) -> EH(R2);
  //          node_hid = gelu([center|NB] @ WtN) -> NH(R3, split-K) ----
  wgemm_t<2, 2, 4>(
      [&](int r, int k, int q) { return ld_sw128(R0, r, k * 4 + q); },
      WtE + (size_t)n0 * 128,
      [&](int mt, int nt, f32x4 acc) {
        int colb = n0 + nt * 16 + lq * 4;
        float4 bb = *(const float4*)(b_edge + colb);
        st_sw128_v4(R2, mt * 16 + lm, colb, pack_gelu4(acc, bb));
      });
  {
    f32x4 ac[2][2];
#pragma unroll
    for (int mt = 0; mt < 2; ++mt)
#pragma unroll
      for (int nt = 0; nt < 2; ++nt) ac[mt][nt] = {0.f, 0.f, 0.f, 0.f};
    wgemm_t_pass<2, 2, 4>(  // k 0..3: center row (broadcast) from global bf16
        [&](int r, int k, int q) {
          (void)r;
          return *(const short8*)(nh_bf + (size_t)base * 128 + k * 32 + q * 8);
        },
        WtN + (size_t)n0 * 256, 256, ac);
    wgemm_t_pass<2, 2, 4>(  // k 4..7: gathered neighbors
        [&](int r, int k, int q) { return ld_sw128(R1, r, k * 4 + q); },
        WtN + (size_t)n0 * 256 + 128, 256, ac);
#pragma unroll
    for (int mt = 0; mt < 2; ++mt)
#pragma unroll
      for (int nt = 0; nt < 2; ++nt) {
        int colb = n0 + nt * 16 + lq * 4;
        float4 bb = *(const float4*)(b_node + colb);
        st_sw128_v4(R3, mt * 16 + lm, colb, pack_gelu4(ac[mt][nt], bb));
      }
  }
  __syncthreads();

  // ---- S3: msg = gelu([EH|NH] @ WtM) -> MS(R0), split-K ----
  {
    f32x4 ac[2][2];
#pragma unroll
    for (int mt = 0; mt < 2; ++mt)
#pragma unroll
      for (int nt = 0; nt < 2; ++nt) ac[mt][nt] = {0.f, 0.f, 0.f, 0.f};
    wgemm_t_pass<2, 2, 4>(
        [&](int r, int k, int q) { return ld_sw128(R2, r, k * 4 + q); },
        WtM + (size_t)n0 * 256, 256, ac);
    wgemm_t_pass<2, 2, 4>(
        [&](int r, int k, int q) { return ld_sw128(R3, r, k * 4 + q); },
        WtM + (size_t)n0 * 256 + 128, 256, ac);
#pragma unroll
    for (int mt = 0; mt < 2; ++mt)
#pragma unroll
      for (int nt = 0; nt < 2; ++nt) {
        int colb = n0 + nt * 16 + lq * 4;
        float4 bb = *(const float4*)(b_msg + colb);
        st_sw128_v4(R0, mt * 16 + lm, colb, pack_gelu4(ac[mt][nt], bb));
      }
  }
  __syncthreads();

  // ---- S4: qkv = MS @ WtQ ; q -> QH(R1) [8][32][16], k -> KH(R2),
  //          v -> VT(R3) [128 rows=v-col][32 m] chunk-swizzled ----
  {
    const int q0 = w * 96;
    wgemm<2, 6, 4>(
        [&](int r, int k, int q) { return ld_sw128(R0, r, k * 4 + q); },
        WtQ + (size_t)q0 * 128,
        [&](int mt, int nt, f32x4 acc) {
          int c = q0 + nt * 16;  // tile-uniform global col base
          float bb = b_qkv[c + lm];
          int m = mt * 16 + lq * 4;
          if (c < 256) {
            short* dst = (c < 128 ? R1 + ((c >> 4) * 32) * 16
                                  : R2 + (((c - 128) >> 4) * 32) * 16);
#pragma unroll
            for (int rr = 0; rr < 4; ++rr)
              dst[(m + rr) * 16 + lm] = f2bf(acc[rr] + bb);
          } else {
            int rv = (c - 256) + lm;  // v column 0..127 -> VT row
            short4v pv;
#pragma unroll
            for (int rr = 0; rr < 4; ++rr) pv[rr] = f2bf(acc[rr] + bb);
            int chv = m >> 3;
            *(short4v*)(R3 + rv * 32 + ((chv ^ (rv & 3)) << 3) + (m & 7)) = pv;
          }
        });
  }
  __syncthreads();

  // ---- S5: 8-head attention, one head instance per wave-iter ----
  {
    const short8 zz = {0, 0, 0, 0, 0, 0, 0, 0};
    const f32x4 z4 = {0.f, 0.f, 0.f, 0.f};
    const int nvv = nvalid[base];
#pragma unroll
    for (int it = 0; it < 2; ++it) {
      int h = (it << 2) | w;
      short* qh = R1 + h * 512;
      short* kh = R2 + h * 512;
      short8 bk[2];
#pragma unroll
      for (int nt = 0; nt < 2; ++nt)
        bk[nt] = (lq < 2) ? *(const short8*)(kh + (nt * 16 + lm) * 16 + lq * 8) : zz;
      float sc[2][2][4];
#pragma unroll
      for (int mt = 0; mt < 2; ++mt) {
        short8 aq = (lq < 2) ? *(const short8*)(qh + (mt * 16 + lm) * 16 + lq * 8) : zz;
#pragma unroll
        for (int nt = 0; nt < 2; ++nt) {
          f32x4 s = mfma16(aq, bk[nt], z4);
#pragma unroll
          for (int rr = 0; rr < 4; ++rr) {
            float x = s[rr] * 0.25f;
            if (nt * 16 + lm >= nvv) x = -1e9f;
            sc[mt][nt][rr] = x;
          }
        }
      }
      // softmax per row (row = mt*16 + lq*4 + rr, cols distributed over lm)
#pragma unroll
      for (int mt = 0; mt < 2; ++mt)
#pragma unroll
        for (int rr = 0; rr < 4; ++rr) {
          float x0 = sc[mt][0][rr], x1 = sc[mt][1][rr];
          float mx = fmaxf(x0, x1);
          mx = fmaxf(mx, __shfl_xor(mx, 1, 16));
          mx = fmaxf(mx, __shfl_xor(mx, 2, 16));
          mx = fmaxf(mx, __shfl_xor(mx, 4, 16));
          mx = fmaxf(mx, __shfl_xor(mx, 8, 16));
          float e0 = __expf(x0 - mx), e1 = __expf(x1 - mx);
          float sm = e0 + e1;
          sm += __shfl_xor(sm, 1, 16);
          sm += __shfl_xor(sm, 2, 16);
          sm += __shfl_xor(sm, 4, 16);
          sm += __shfl_xor(sm, 8, 16);
          float ri = 1.f / sm;
          int row = mt * 16 + lq * 4 + rr;
          qh[row * 16 + lm] = f2bf(e0 * ri);  // P cols 0-15
          kh[row * 16 + lm] = f2bf(e1 * ri);  // P cols 16-31
        }
      // PV: A = P (K=32), B = VT head rows -> ctx into CX(R0)
#pragma unroll
      for (int mt = 0; mt < 2; ++mt) {
        const short* psrc = (lq < 2) ? qh : kh;
        short8 pa = *(const short8*)(psrc + (mt * 16 + lm) * 16 + (lq & 1) * 8);
        int rv = h * 16 + lm;
        short8 vb = *(const short8*)(R3 + rv * 32 + ((lq ^ (rv & 3)) << 3));
        f32x4 c = mfma16(pa, vb, z4);
#pragma unroll
        for (int rr = 0; rr < 4; ++rr)
          st_sw128(R0, mt * 16 + lq * 4 + rr, h * 16 + lm, f2bf(c[rr]));
      }
    }
  }
  __syncthreads();

  // ---- S6: edge_out = CX @ WtO + b_out; R(R1) = edge_out + ef (bf16);
  //          node_res = sum_{k<nv} edge_out + nf -> out_node ----
  {
    int nv = nvalid[base];
    float nsum[2] = {0.f, 0.f};
    wgemm<2, 2, 4>(
        [&](int r, int k, int q) { return ld_sw128(R0, r, k * 4 + q); },
        WtO + (size_t)n0 * 128,
        [&](int mt, int nt, f32x4 acc) {
          int col = n0 + nt * 16 + lm;
          float bb = b_out[col];
#pragma unroll
          for (int rr = 0; rr < 4; ++rr) {
            int kk = mt * 16 + lq * 4 + rr;
            float eo = acc[rr] + bb;
            if (kk < nv) nsum[nt] += eo;
            float efv = ef[((size_t)base * KNBR + kk) * 128 + col];
            st_sw128(R1, kk, col, f2bf(eo + efv));
          }
        });
#pragma unroll
    for (int nt = 0; nt < 2; ++nt) {
      float v = nsum[nt];
      v += __shfl_xor(v, 16, 64);
      v += __shfl_xor(v, 32, 64);
      if (lq == 0) {
        int col = n0 + nt * 16 + lm;
        out_node[(size_t)base * 128 + col] =
            v + nf[(size_t)base * 128 + col];
      }
    }
  }
  __syncthreads();

  // ---- S7: EHN(R0) = LayerNorm(R) (scratch in R2) ----
  {
    float* scr = (float*)R2;
    int r = tid >> 3, sg = tid & 7;
    short8 xv[2];
    float s = 0.f, s2 = 0.f;
#pragma unroll
    for (int j = 0; j < 2; ++j) {
      int ch = sg * 2 + j;
      xv[j] = *(const short8*)(R1 + r * 128 + ((ch ^ (r & 7)) << 3));
#pragma unroll
      for (int e = 0; e < 8; ++e) {
        float x = bf2f(xv[j][e]);
        s += x;
        s2 = fmaf(x, x, s2);
      }
    }
    scr[r * 8 + sg] = s;
    scr[256 + r * 8 + sg] = s2;
    __syncthreads();
    if (tid < 32) {
      float ss = 0.f, q2 = 0.f;
#pragma unroll
      for (int i = 0; i < 8; ++i) { ss += scr[tid * 8 + i]; q2 += scr[256 + tid * 8 + i]; }
      float mn = ss * (1.f / 128.f);
      float vr = fmaf(-mn, mn, q2 * (1.f / 128.f));
      scr[512 + tid * 2] = mn;
      scr[512 + tid * 2 + 1] = rsqrtf(vr + 1e-5f);
    }
    __syncthreads();
    float mn = scr[512 + r * 2], rs = scr[512 + r * 2 + 1];
#pragma unroll
    for (int j = 0; j < 2; ++j) {
      int ch = sg * 2 + j;
      int c0 = ch * 8;
      float4 g0 = *(const float4*)(g_fe + c0);
      float4 g1 = *(const float4*)(g_fe + c0 + 4);
      float4 b0 = *(const float4*)(be_fe + c0);
      float4 b1 = *(const float4*)(be_fe + c0 + 4);
      const float* gp0 = (const float*)&g0;
      const float* gp1 = (const float*)&g1;
      const float* bp0 = (const float*)&b0;
      const float* bp1 = (const float*)&b1;
      short8 ov;
#pragma unroll
      for (int e = 0; e < 4; ++e) {
        ov[e] = f2bf(fmaf((bf2f(xv[j][e]) - mn) * rs, gp0[e], bp0[e]));
        ov[4 + e] = f2bf(fmaf((bf2f(xv[j][4 + e]) - mn) * rs, gp1[e], bp1[e]));
      }
      *(short8*)(R0 + r * 128 + ((ch ^ (r & 7)) << 3)) = ov;
    }
  }
  __syncthreads();

  // ---- S8: HID(R2..R3) = gelu(EHN @ WtE1 + be1), [32][256] swizzled ----
  {
    const int f0 = w * 64;
    wgemm_t<2, 4, 4>(
        [&](int r, int k, int q) { return ld_sw128(R0, r, k * 4 + q); },
        WtE1 + (size_t)f0 * 128,
        [&](int mt, int nt, f32x4 acc) {
          int colb = f0 + nt * 16 + lq * 4;
          float4 bb = *(const float4*)(be1 + colb);
          st_sw256_v4(R2, mt * 16 + lm, colb, pack_gelu4(acc, bb));
        });
  }
  __syncthreads();

  // ---- S9: out_edge = R + HID @ WtE2 + be2 (fp32 global stores), split-K ----
  {
    f32x4 ac[2][2];
#pragma unroll
    for (int mt = 0; mt < 2; ++mt)
#pragma unroll
      for (int nt = 0; nt < 2; ++nt) ac[mt][nt] = {0.f, 0.f, 0.f, 0.f};
    wgemm_pass<2, 2, 4>(
        [&](int r, int k, int q) { return ld_sw256(R2, r, k * 4 + q); },
        WtE2 + (size_t)n0 * 256, 256, ac);
    wgemm_pass<2, 2, 4>(
        [&](int r, int k, int q) { return ld_sw256(R2, r, 16 + k * 4 + q); },
        WtE2 + (size_t)n0 * 256 + 128, 256, ac);
#pragma unroll
    for (int mt = 0; mt < 2; ++mt)
#pragma unroll
      for (int nt = 0; nt < 2; ++nt) {
        int col = n0 + nt * 16 + lm;
        float bb = be2[col];
#pragma unroll
        for (int rr = 0; rr < 4; ++rr) {
          int m = mt * 16 + lq * 4 + rr;
          float rv = bf2f(R1[m * 128 + ((((col >> 3) ^ (m & 7))) << 3) + (col & 7)]);
          out_edge[((size_t)base * KNBR + m) * 128 + col] =
              rv + ac[mt][nt][rr] + bb;
        }
      }
  }
}

// ---------------- kernel 3: node FFN (16 nodes/block, MFMA) ----------------
__global__ __launch_bounds__(256, 4) void node_ffn_kernel(
    const float* __restrict__ nres, const float* __restrict__ g,
    const float* __restrict__ be, const short* __restrict__ WtN1,
    const float* __restrict__ bn1, const short* __restrict__ WtN2,
    const float* __restrict__ bn2, float* __restrict__ out) {
  __shared__ short lds[8192];
  short* EHN = lds;                    // [16][128] swizzled bf16 (2048 shorts)
  float* scr = (float*)(lds + 2048);   // 544 floats scratch
  short* HID = lds + 4096;             // [16][256] swizzled bf16 (4096 shorts)

  const int tid = threadIdx.x;
  const int w = tid >> 6;
  const int lane = tid & 63;
  const int lm = lane & 15, lq = lane >> 4;
  const int base = blockIdx.x * 16;
  const int n0 = w * 32;

  // LN from global node_res (fp32) -> EHN
  {
    int r = tid >> 4, sg = tid & 15;
    bool valid = (base + r) < N_NODES;
    float xf[8];
#pragma unroll
    for (int i = 0; i < 2; ++i) {
      float4 v = valid ? ((const float4*)(nres + (size_t)(base + r) * 128 + sg * 8))[i]
                       : make_float4(0.f, 0.f, 0.f, 0.f);
      xf[i * 4] = v.x; xf[i * 4 + 1] = v.y; xf[i * 4 + 2] = v.z; xf[i * 4 + 3] = v.w;
    }
    float s = 0.f, s2 = 0.f;
#pragma unroll
    for (int i = 0; i < 8; ++i) { s += xf[i]; s2 = fmaf(xf[i], xf[i], s2); }
    scr[r * 16 + sg] = s;
    scr[256 + r * 16 + sg] = s2;
    __syncthreads();
    if (tid < 16) {
      float ss = 0.f, q2 = 0.f;
#pragma unroll
      for (int i = 0; i < 16; ++i) { ss += scr[tid * 16 + i]; q2 += scr[256 + tid * 16 + i]; }
      float mn = ss * (1.f / 128.f);
      float vr = fmaf(-mn, mn, q2 * (1.f / 128.f));
      scr[512 + tid * 2] = mn;
      scr[512 + tid * 2 + 1] = rsqrtf(vr + 1e-5f);
    }
    __syncthreads();
    float mn = scr[512 + r * 2], rs = scr[512 + r * 2 + 1];
    int c0 = sg * 8;
    short8 ov;
#pragma unroll
    for (int e = 0; e < 8; ++e)
      ov[e] = f2bf(fmaf((xf[e] - mn) * rs, g[c0 + e], be[c0 + e]));
    *(short8*)(EHN + r * 128 + ((sg ^ (r & 7)) << 3)) = ov;
  }
  __syncthreads();

  // hidden = gelu(EHN @ WtN1 + bn1)
  {
    const int f0 = w * 64;
    wgemm_t<1, 4, 4>(
        [&](int r, int k, int q) { return ld_sw128(EHN, r, k * 4 + q); },
        WtN1 + (size_t)f0 * 128,
        [&](int mt, int nt, f32x4 acc) {
          int colb = f0 + nt * 16 + lq * 4;
          float4 bb = *(const float4*)(bn1 + colb);
          st_sw256_v4(HID, mt * 16 + lm, colb, pack_gelu4(acc, bb));
        });
  }
  __syncthreads();

  // out = node_res + hidden @ WtN2 + bn2 (split-K)
  {
    f32x4 ac[1][2];
    ac[0][0] = {0.f, 0.f, 0.f, 0.f};
    ac[0][1] = {0.f, 0.f, 0.f, 0.f};
    wgemm_pass<1, 2, 4>(
        [&](int r, int k, int q) { return ld_sw256(HID, r, k * 4 + q); },
        WtN2 + (size_t)n0 * 256, 256, ac);
    wgemm_pass<1, 2, 4>(
        [&](int r, int k, int q) { return ld_sw256(HID, r, 16 + k * 4 + q); },
        WtN2 + (size_t)n0 * 256 + 128, 256, ac);
#pragma unroll
    for (int nt = 0; nt < 2; ++nt) {
      int col = n0 + nt * 16 + lm;
      float bb = bn2[col];
#pragma unroll
      for (int rr = 0; rr < 4; ++rr) {
        int m = lq * 4 + rr;
        if (base + m < N_NODES) {
          float rv = nres[(size_t)(base + m) * 128 + col];
          out[(size_t)(base + m) * 128 + col] = rv + ac[0][nt][rr] + bb;
        }
      }
    }
  }
}

// ---------------- launch ----------------
extern "C" void kernel_launch(void* const* d_in, const int* in_sizes, int n_in,
                              void* d_out, int out_size, void* d_ws,
                              size_t ws_size, hipStream_t stream) {
  (void)in_sizes; (void)n_in; (void)out_size; (void)ws_size;
  const float* nf = (const float*)d_in[0];
  const float* ef = (const float*)d_in[1];
  const float* ea = (const float*)d_in[2];
  const int* nlist = (const int*)d_in[3];
  const int* nvalid = (const int*)d_in[4];
  const float* W_edge = (const float*)d_in[5];
  const float* b_edge = (const float*)d_in[6];
  const float* W_node = (const float*)d_in[7];
  const float* b_node = (const float*)d_in[8];
  const float* W_msg = (const float*)d_in[9];
  const float* b_msg = (const float*)d_in[10];
  const float* W_qkv = (const float*)d_in[11];
  const float* b_qkv = (const float*)d_in[12];
  const float* W_out = (const float*)d_in[13];
  const float* b_out = (const float*)d_in[14];
  const float* g_attn = (const float*)d_in[15];
  const float* be_attn = (const float*)d_in[16];
  const float* g_fn = (const float*)d_in[17];
  const float* be_fn = (const float*)d_in[18];
  const float* g_fe = (const float*)d_in[19];
  const float* be_fe = (const float*)d_in[20];
  const float* Wn1 = (const float*)d_in[21];
  const float* bn1 = (const float*)d_in[22];
  const float* Wn2 = (const float*)d_in[23];
  const float* bn2 = (const float*)d_in[24];
  const float* We1 = (const float*)d_in[25];
  const float* be1 = (const float*)d_in[26];
  const float* We2 = (const float*)d_in[27];
  const float* be2 = (const float*)d_in[28];

  short* ws0 = (short*)d_ws;           // node_hidden bf16 [N][128]
  short* wsW = ws0 + 1280000;          // transposed bf16 weights, 278528 elems
  short* WtE = wsW;
  short* WtN = wsW + 16384;
  short* WtM = wsW + 49152;
  short* WtQ = wsW + 81920;
  short* WtO = wsW + 131072;
  short* WtE1 = wsW + 147456;
  short* WtE2 = wsW + 180224;
  short* WtN1 = wsW + 212992;
  short* WtN2 = wsW + 245760;

  float* out_node = (float*)d_out;
  float* out_edge = out_node + (size_t)N_NODES * 128;

  WSrc wsrc;
  wsrc.p[0] = W_edge; wsrc.p[1] = W_node; wsrc.p[2] = W_msg;
  wsrc.p[3] = W_qkv;  wsrc.p[4] = W_out;  wsrc.p[5] = We1;
  wsrc.p[6] = We2;    wsrc.p[7] = Wn1;    wsrc.p[8] = Wn2;

  wprep_kernel<<<1088, 256, 0, stream>>>(wsrc, wsW);
  ln_in_kernel<<<(N_NODES + 31) / 32, 256, 0, stream>>>(nf, g_attn, be_attn, ws0);
  egab_main<<<N_NODES, 256, 0, stream>>>(
      nf, ef, ea, nlist, nvalid, b_edge, b_node, b_msg, b_qkv, b_out, g_fe,
      be_fe, be1, be2, WtE, WtN, WtM, WtQ, WtO, WtE1, WtE2, ws0, out_node,
      out_edge);
  node_ffn_kernel<<<(N_NODES + 15) / 16, 256, 0, stream>>>(
      out_node, g_fn, be_fn, WtN1, bn1, WtN2, bn2, out_node);
}

// Round 9
// 889.336 us; speedup vs baseline: 1.1498x; 1.0037x over previous
//
#include <hip/hip_runtime.h>
#include <hip/hip_bf16.h>
#include <cstddef>

#define N_NODES 10000
#define KNBR 32
#define HDIM 128
#define NHEADS 8

using short8 = __attribute__((ext_vector_type(8))) short;
using short4v = __attribute__((ext_vector_type(4))) short;
using f32x4 = __attribute__((ext_vector_type(4))) float;

__device__ __forceinline__ f32x4 mfma16(short8 a, short8 b, f32x4 c) {
  return __builtin_amdgcn_mfma_f32_16x16x32_bf16(a, b, c, 0, 0, 0);
}

// HW bf16 convert (RNE)
__device__ __forceinline__ short f2bf(float f) {
  __hip_bfloat16 h = __float2bfloat16(f);
  return __builtin_bit_cast(short, h);
}
__device__ __forceinline__ float bf2f(short s) {
  unsigned u = ((unsigned)(unsigned short)s) << 16;
  return __builtin_bit_cast(float, u);
}

// tanh-approx gelu == x * sigmoid(1.59577x + 0.0713548x^3), exp folded into
// exp2 + rcp (~7 VALU ops vs ~15 for the divide form). Verified R7 (absmax ok).
__device__ __forceinline__ float gelu_f(float x) {
  float u = x * fmaf(x * x, -0.1029432f, -2.3022077f);
  return x * __builtin_amdgcn_rcpf(1.0f + __builtin_amdgcn_exp2f(u));
}

__device__ __forceinline__ short4v pack4f(float a, float b, float c, float d) {
  short4v v; v[0] = f2bf(a); v[1] = f2bf(b); v[2] = f2bf(c); v[3] = f2bf(d);
  return v;
}
__device__ __forceinline__ short4v pack_gelu4(f32x4 acc, float4 bb) {
  return pack4f(gelu_f(acc[0] + bb.x), gelu_f(acc[1] + bb.y),
                gelu_f(acc[2] + bb.z), gelu_f(acc[3] + bb.w));
}

// Swizzled LDS tiles: row-major [rows][128 or 256] bf16, 16B chunk c of row r
// stored at physical chunk (c ^ (r&7)). Conflict-free A-frag ds_read_b128.
__device__ __forceinline__ short8 ld_sw128(const short* b, int r, int ch) {
  return *(const short8*)(b + r * 128 + (((ch ^ (r & 7))) << 3));
}
__device__ __forceinline__ short8 ld_sw256(const short* b, int r, int ch) {
  return *(const short8*)(b + r * 256 + (((ch ^ (r & 7))) << 3));
}
__device__ __forceinline__ void st_sw128(short* b, int r, int col, short v) {
  b[r * 128 + ((((col >> 3) ^ (r & 7))) << 3) + (col & 7)] = v;
}
// b64 store of 4 consecutive cols (colb aligned to 4) of row r
__device__ __forceinline__ void st_sw128_v4(short* b, int r, int colb, short4v v) {
  *(short4v*)(b + r * 128 + ((((colb >> 3) ^ (r & 7))) << 3) + (colb & 7)) = v;
}
__device__ __forceinline__ void st_sw256_v4(short* b, int r, int colb, short4v v) {
  *(short4v*)(b + r * 256 + ((((colb >> 3) ^ (r & 7))) << 3) + (colb & 7)) = v;
}

// ---- Per-wave MFMA GEMM building blocks -----------------------------------
// Single-shot forms (KS<=4): A-preload (R3-proven ILP), transient acc.
// Split-K pass forms: nt-outer/mt-inner with per-(nt,mt) A-re-read from LDS.
// R8 lesson: a[MT][KS] persistent across the nt loop (32 regs) + acc (16) +
// b (16) exceeded the 64-VGPR slice of __launch_bounds__(256,4) -> ~6 dwords
// of scratch per thread (WRITE 165->225MB). Per-group A-re-read costs 8 extra
// L1/LDS reads per pass but caps liveness at b16+a16+acc16 ~= 48.

// Normal: epi acc[rr] = C[row = mt*16 + lq*4 + rr][col = nt*16 + lm].
template <int MT, int NT, int KS, typename ALoad, typename Epi>
__device__ __forceinline__ void wgemm(ALoad aload, const short* __restrict__ Bt,
                                      Epi epi) {
  const int lane = threadIdx.x & 63;
  const int lm = lane & 15, lq = lane >> 4;
  short8 a[MT][KS];
#pragma unroll
  for (int mt = 0; mt < MT; ++mt)
#pragma unroll
    for (int k = 0; k < KS; ++k) a[mt][k] = aload(mt * 16 + lm, k, lq);
#pragma unroll
  for (int nt = 0; nt < NT; ++nt) {
    short8 b[KS];
#pragma unroll
    for (int k = 0; k < KS; ++k)
      b[k] = *(const short8*)(Bt + (nt * 16 + lm) * (KS * 32) + k * 32 + lq * 8);
#pragma unroll
    for (int mt = 0; mt < MT; ++mt) {
      f32x4 acc = {0.f, 0.f, 0.f, 0.f};
#pragma unroll
      for (int k = 0; k < KS; ++k) acc = mfma16(a[mt][k], b[k], acc);
      epi(mt, nt, acc);
    }
  }
}

// Transposed single-shot (operands swapped; legal, verified R5):
// epi acc[rr] = C[row = mt*16 + lm][col = nt*16 + lq*4 + rr].
template <int MT, int NT, int KS, typename ALoad, typename Epi>
__device__ __forceinline__ void wgemm_t(ALoad aload, const short* __restrict__ Bt,
                                        Epi epi) {
  const int lane = threadIdx.x & 63;
  const int lm = lane & 15, lq = lane >> 4;
  short8 a[MT][KS];
#pragma unroll
  for (int mt = 0; mt < MT; ++mt)
#pragma unroll
    for (int k = 0; k < KS; ++k) a[mt][k] = aload(mt * 16 + lm, k, lq);
#pragma unroll
  for (int nt = 0; nt < NT; ++nt) {
    short8 b[KS];
#pragma unroll
    for (int k = 0; k < KS; ++k)
      b[k] = *(const short8*)(Bt + (nt * 16 + lm) * (KS * 32) + k * 32 + lq * 8);
#pragma unroll
    for (int mt = 0; mt < MT; ++mt) {
      f32x4 acc = {0.f, 0.f, 0.f, 0.f};
#pragma unroll
      for (int k = 0; k < KS; ++k) acc = mfma16(b[k], a[mt][k], acc);
      epi(mt, nt, acc);
    }
  }
}

// Split-K pass, low-pressure: accumulates into caller's acc. brs = B row
// stride (elements): a KS=8 weight layout (stride 256) is consumed in two
// KS=4 passes (second pass: Bt += 128). A re-read per (nt,mt) group.
template <int MT, int NT, int KS, typename ALoad>
__device__ __forceinline__ void wgemm_pass(ALoad aload,
                                           const short* __restrict__ Bt,
                                           int brs, f32x4 (&acc)[MT][NT]) {
  const int lane = threadIdx.x & 63;
  const int lm = lane & 15, lq = lane >> 4;
#pragma unroll
  for (int nt = 0; nt < NT; ++nt) {
    short8 b[KS];
#pragma unroll
    for (int k = 0; k < KS; ++k)
      b[k] = *(const short8*)(Bt + (nt * 16 + lm) * brs + k * 32 + lq * 8);
#pragma unroll
    for (int mt = 0; mt < MT; ++mt) {
      short8 a[KS];
#pragma unroll
      for (int k = 0; k < KS; ++k) a[k] = aload(mt * 16 + lm, k, lq);
#pragma unroll
      for (int k = 0; k < KS; ++k)
        acc[mt][nt] = mfma16(a[k], b[k], acc[mt][nt]);
    }
  }
}

template <int MT, int NT, int KS, typename ALoad>
__device__ __forceinline__ void wgemm_t_pass(ALoad aload,
                                             const short* __restrict__ Bt,
                                             int brs, f32x4 (&acc)[MT][NT]) {
  const int lane = threadIdx.x & 63;
  const int lm = lane & 15, lq = lane >> 4;
#pragma unroll
  for (int nt = 0; nt < NT; ++nt) {
    short8 b[KS];
#pragma unroll
    for (int k = 0; k < KS; ++k)
      b[k] = *(const short8*)(Bt + (nt * 16 + lm) * brs + k * 32 + lq * 8);
#pragma unroll
    for (int mt = 0; mt < MT; ++mt) {
      short8 a[KS];
#pragma unroll
      for (int k = 0; k < KS; ++k) a[k] = aload(mt * 16 + lm, k, lq);
#pragma unroll
      for (int k = 0; k < KS; ++k)
        acc[mt][nt] = mfma16(b[k], a[k], acc[mt][nt]);
    }
  }
}

// ---------------- kernel 0: weights -> bf16 transposed in ws ----------------
struct WSrc { const float* p[9]; };

__global__ void wprep_kernel(WSrc ws, short* __restrict__ dst) {
  const int cum[10] = {0, 16384, 49152, 81920, 131072, 147456, 180224, 212992, 245760, 278528};
  const int Ks[9] = {128, 256, 256, 128, 128, 128, 256, 128, 256};
  const int Ns[9] = {128, 128, 128, 384, 128, 256, 128, 256, 128};
  int eg = blockIdx.x * 256 + threadIdx.x;
  int id = 0;
#pragma unroll
  for (int i = 0; i < 8; ++i) id += (eg >= cum[i + 1]) ? 1 : 0;
  int e = eg - cum[id];
  int K = Ks[id];
  int n = (K == 128) ? (e >> 7) : (e >> 8);
  int k = e - n * K;
  dst[eg] = f2bf(ws.p[id][k * Ns[id] + n]);
}

// ---------------- kernel 1: LN(node_features) -> bf16 ws0 ----------------
__global__ __launch_bounds__(256) void ln_in_kernel(
    const float* __restrict__ in, const float* __restrict__ g,
    const float* __restrict__ be, short* __restrict__ out) {
  __shared__ float scr[32 * 8 * 2 + 64];
  const int tid = threadIdx.x;
  const int r = tid >> 3, j = tid & 7;
  const int base = blockIdx.x * 32;
  const int rg = base + r;
  const bool valid = rg < N_NODES;
  float4 v[4];
#pragma unroll
  for (int i = 0; i < 4; ++i)
    v[i] = valid ? ((const float4*)(in + (size_t)rg * 128 + j * 16))[i]
                 : make_float4(0.f, 0.f, 0.f, 0.f);
  float s = 0.f, s2 = 0.f;
#pragma unroll
  for (int i = 0; i < 4; ++i) {
    s += v[i].x + v[i].y + v[i].z + v[i].w;
    s2 = fmaf(v[i].x, v[i].x, s2); s2 = fmaf(v[i].y, v[i].y, s2);
    s2 = fmaf(v[i].z, v[i].z, s2); s2 = fmaf(v[i].w, v[i].w, s2);
  }
  scr[r * 8 + j] = s;
  scr[256 + r * 8 + j] = s2;
  __syncthreads();
  if (tid < 32) {
    float ss = 0.f, q2 = 0.f;
#pragma unroll
    for (int i = 0; i < 8; ++i) { ss += scr[tid * 8 + i]; q2 += scr[256 + tid * 8 + i]; }
    float mn = ss * (1.f / 128.f);
    float vr = fmaf(-mn, mn, q2 * (1.f / 128.f));
    scr[512 + tid] = mn;
    scr[544 + tid] = rsqrtf(vr + 1e-5f);
  }
  __syncthreads();
  if (!valid) return;
  float mn = scr[512 + r], rs = scr[544 + r];
  short8 o[2];
#pragma unroll
  for (int i = 0; i < 4; ++i) {
    int c0 = j * 16 + i * 4;
    float4 gg = *(const float4*)(g + c0);
    float4 bb = *(const float4*)(be + c0);
    float* vf = (float*)&v[i];
    float* gf = (float*)&gg;
    float* bf = (float*)&bb;
#pragma unroll
    for (int e = 0; e < 4; ++e)
      o[i >> 1][(i & 1) * 4 + e] = f2bf(fmaf((vf[e] - mn) * rs, gf[e], bf[e]));
  }
  *(short8*)(out + (size_t)rg * 128 + j * 16) = o[0];
  *(short8*)(out + (size_t)rg * 128 + j * 16 + 8) = o[1];
}

// ---------------- kernel 2: fused per-node block (MFMA), 1 node/block -------
// 32KB LDS, __launch_bounds__(256,4): split-K KS=4 passes with per-group
// A-re-read keep peak liveness ~48 regs -> 4 waves/SIMD spill-free.
// Spill tripwire: WRITE_SIZE must be ~165MB.
// Regions (8KB each, [32][128] bf16): lifetime-aliased:
// R0: EA -> MS -> CX -> EHN ; R1: NB -> QH(+P) -> R(res bf16)
// R2: EH -> KH(+P) -> LNscr -> HID.lo ; R3: NH -> VT -> HID.hi
__global__ __launch_bounds__(256, 4) void egab_main(
    const float* __restrict__ nf, const float* __restrict__ ef,
    const float* __restrict__ ea, const int* __restrict__ nlist,
    const int* __restrict__ nvalid,
    const float* __restrict__ b_edge, const float* __restrict__ b_node,
    const float* __restrict__ b_msg, const float* __restrict__ b_qkv,
    const float* __restrict__ b_out, const float* __restrict__ g_fe,
    const float* __restrict__ be_fe, const float* __restrict__ be1,
    const float* __restrict__ be2,
    const short* __restrict__ WtE, const short* __restrict__ WtN,
    const short* __restrict__ WtM, const short* __restrict__ WtQ,
    const short* __restrict__ WtO, const short* __restrict__ WtE1,
    const short* __restrict__ WtE2, const short* __restrict__ nh_bf,
    float* __restrict__ out_node, float* __restrict__ out_edge) {
  __shared__ short lds[16384];
  short* R0 = lds;
  short* R1 = lds + 4096;
  short* R2 = lds + 8192;
  short* R3 = lds + 12288;

  const int tid = threadIdx.x;
  const int w = tid >> 6;
  const int lane = tid & 63;
  const int lm = lane & 15, lq = lane >> 4;
  const int base = blockIdx.x;      // 1 node per block
  const int n0 = w * 32;            // wave col slice for Nout=128 GEMMs

  // ---- S1: edge_attr -> EA(R0) bf16 swizzled; gather neighbors -> NB(R1) ----
  {
    const float* eap = ea + (size_t)base * 4096;
    int r = tid >> 3;
    int sg = tid & 7;
#pragma unroll
    for (int j = 0; j < 2; ++j) {
      int ch = sg * 2 + j;
      float4 fa = ((const float4*)eap)[r * 32 + ch * 2];
      float4 fb = ((const float4*)eap)[r * 32 + ch * 2 + 1];
      short8 v = {f2bf(fa.x), f2bf(fa.y), f2bf(fa.z), f2bf(fa.w),
                  f2bf(fb.x), f2bf(fb.y), f2bf(fb.z), f2bf(fb.w)};
      *(short8*)(R0 + r * 128 + ((ch ^ (r & 7)) << 3)) = v;
    }
    int idx = nlist[base * KNBR + r];
    const short* srow = nh_bf + (size_t)idx * 128;
#pragma unroll
    for (int j = 0; j < 2; ++j) {
      int ch = sg * 2 + j;
      short8 v = *(const short8*)(srow + ch * 8);
      *(short8*)(R1 + r * 128 + ((ch ^ (r & 7)) << 3)) = v;
    }
  }
  __syncthreads();

  // ---- S2: edge_hidden = gelu(EA @ WtE) -> EH(R2);
  //          node_hid = gelu([center|NB] @ WtN) -> NH(R3, split-K) ----
  wgemm_t<2, 2, 4>(
      [&](int r, int k, int q) { return ld_sw128(R0, r, k * 4 + q); },
      WtE + (size_t)n0 * 128,
      [&](int mt, int nt, f32x4 acc) {
        int colb = n0 + nt * 16 + lq * 4;
        float4 bb = *(const float4*)(b_edge + colb);
        st_sw128_v4(R2, mt * 16 + lm, colb, pack_gelu4(acc, bb));
      });
  {
    f32x4 ac[2][2];
#pragma unroll
    for (int mt = 0; mt < 2; ++mt)
#pragma unroll
      for (int nt = 0; nt < 2; ++nt) ac[mt][nt] = {0.f, 0.f, 0.f, 0.f};
    wgemm_t_pass<2, 2, 4>(  // k 0..3: center row (broadcast) from global bf16
        [&](int r, int k, int q) {
          (void)r;
          return *(const short8*)(nh_bf + (size_t)base * 128 + k * 32 + q * 8);
        },
        WtN + (size_t)n0 * 256, 256, ac);
    wgemm_t_pass<2, 2, 4>(  // k 4..7: gathered neighbors
        [&](int r, int k, int q) { return ld_sw128(R1, r, k * 4 + q); },
        WtN + (size_t)n0 * 256 + 128, 256, ac);
#pragma unroll
    for (int mt = 0; mt < 2; ++mt)
#pragma unroll
      for (int nt = 0; nt < 2; ++nt) {
        int colb = n0 + nt * 16 + lq * 4;
        float4 bb = *(const float4*)(b_node + colb);
        st_sw128_v4(R3, mt * 16 + lm, colb, pack_gelu4(ac[mt][nt], bb));
      }
  }
  __syncthreads();

  // ---- S3: msg = gelu([EH|NH] @ WtM) -> MS(R0), split-K ----
  {
    f32x4 ac[2][2];
#pragma unroll
    for (int mt = 0; mt < 2; ++mt)
#pragma unroll
      for (int nt = 0; nt < 2; ++nt) ac[mt][nt] = {0.f, 0.f, 0.f, 0.f};
    wgemm_t_pass<2, 2, 4>(
        [&](int r, int k, int q) { return ld_sw128(R2, r, k * 4 + q); },
        WtM + (size_t)n0 * 256, 256, ac);
    wgemm_t_pass<2, 2, 4>(
        [&](int r, int k, int q) { return ld_sw128(R3, r, k * 4 + q); },
        WtM + (size_t)n0 * 256 + 128, 256, ac);
#pragma unroll
    for (int mt = 0; mt < 2; ++mt)
#pragma unroll
      for (int nt = 0; nt < 2; ++nt) {
        int colb = n0 + nt * 16 + lq * 4;
        float4 bb = *(const float4*)(b_msg + colb);
        st_sw128_v4(R0, mt * 16 + lm, colb, pack_gelu4(ac[mt][nt], bb));
      }
  }
  __syncthreads();

  // ---- S4: qkv = MS @ WtQ ; q -> QH(R1) [8][32][16], k -> KH(R2),
  //          v -> VT(R3) [128 rows=v-col][32 m] chunk-swizzled ----
  {
    const int q0 = w * 96;
    wgemm<2, 6, 4>(
        [&](int r, int k, int q) { return ld_sw128(R0, r, k * 4 + q); },
        WtQ + (size_t)q0 * 128,
        [&](int mt, int nt, f32x4 acc) {
          int c = q0 + nt * 16;  // tile-uniform global col base
          float bb = b_qkv[c + lm];
          int m = mt * 16 + lq * 4;
          if (c < 256) {
            short* dst = (c < 128 ? R1 + ((c >> 4) * 32) * 16
                                  : R2 + (((c - 128) >> 4) * 32) * 16);
#pragma unroll
            for (int rr = 0; rr < 4; ++rr)
              dst[(m + rr) * 16 + lm] = f2bf(acc[rr] + bb);
          } else {
            int rv = (c - 256) + lm;  // v column 0..127 -> VT row
            short4v pv;
#pragma unroll
            for (int rr = 0; rr < 4; ++rr) pv[rr] = f2bf(acc[rr] + bb);
            int chv = m >> 3;
            *(short4v*)(R3 + rv * 32 + ((chv ^ (rv & 3)) << 3) + (m & 7)) = pv;
          }
        });
  }
  __syncthreads();

  // ---- S5: 8-head attention, one head instance per wave-iter ----
  {
    const short8 zz = {0, 0, 0, 0, 0, 0, 0, 0};
    const f32x4 z4 = {0.f, 0.f, 0.f, 0.f};
    const int nvv = nvalid[base];
#pragma unroll
    for (int it = 0; it < 2; ++it) {
      int h = (it << 2) | w;
      short* qh = R1 + h * 512;
      short* kh = R2 + h * 512;
      short8 bk[2];
#pragma unroll
      for (int nt = 0; nt < 2; ++nt)
        bk[nt] = (lq < 2) ? *(const short8*)(kh + (nt * 16 + lm) * 16 + lq * 8) : zz;
      float sc[2][2][4];
#pragma unroll
      for (int mt = 0; mt < 2; ++mt) {
        short8 aq = (lq < 2) ? *(const short8*)(qh + (mt * 16 + lm) * 16 + lq * 8) : zz;
#pragma unroll
        for (int nt = 0; nt < 2; ++nt) {
          f32x4 s = mfma16(aq, bk[nt], z4);
#pragma unroll
          for (int rr = 0; rr < 4; ++rr) {
            float x = s[rr] * 0.25f;
            if (nt * 16 + lm >= nvv) x = -1e9f;
            sc[mt][nt][rr] = x;
          }
        }
      }
      // softmax per row (row = mt*16 + lq*4 + rr, cols distributed over lm)
#pragma unroll
      for (int mt = 0; mt < 2; ++mt)
#pragma unroll
        for (int rr = 0; rr < 4; ++rr) {
          float x0 = sc[mt][0][rr], x1 = sc[mt][1][rr];
          float mx = fmaxf(x0, x1);
          mx = fmaxf(mx, __shfl_xor(mx, 1, 16));
          mx = fmaxf(mx, __shfl_xor(mx, 2, 16));
          mx = fmaxf(mx, __shfl_xor(mx, 4, 16));
          mx = fmaxf(mx, __shfl_xor(mx, 8, 16));
          float e0 = __expf(x0 - mx), e1 = __expf(x1 - mx);
          float sm = e0 + e1;
          sm += __shfl_xor(sm, 1, 16);
          sm += __shfl_xor(sm, 2, 16);
          sm += __shfl_xor(sm, 4, 16);
          sm += __shfl_xor(sm, 8, 16);
          float ri = 1.f / sm;
          int row = mt * 16 + lq * 4 + rr;
          qh[row * 16 + lm] = f2bf(e0 * ri);  // P cols 0-15
          kh[row * 16 + lm] = f2bf(e1 * ri);  // P cols 16-31
        }
      // PV: A = P (K=32), B = VT head rows -> ctx into CX(R0)
#pragma unroll
      for (int mt = 0; mt < 2; ++mt) {
        const short* psrc = (lq < 2) ? qh : kh;
        short8 pa = *(const short8*)(psrc + (mt * 16 + lm) * 16 + (lq & 1) * 8);
        int rv = h * 16 + lm;
        short8 vb = *(const short8*)(R3 + rv * 32 + ((lq ^ (rv & 3)) << 3));
        f32x4 c = mfma16(pa, vb, z4);
#pragma unroll
        for (int rr = 0; rr < 4; ++rr)
          st_sw128(R0, mt * 16 + lq * 4 + rr, h * 16 + lm, f2bf(c[rr]));
      }
    }
  }
  __syncthreads();

  // ---- S6: edge_out = CX @ WtO + b_out; R(R1) = edge_out + ef (bf16);
  //          node_res = sum_{k<nv} edge_out + nf -> out_node ----
  {
    int nv = nvalid[base];
    float nsum[2] = {0.f, 0.f};
    wgemm<2, 2, 4>(
        [&](int r, int k, int q) { return ld_sw128(R0, r, k * 4 + q); },
        WtO + (size_t)n0 * 128,
        [&](int mt, int nt, f32x4 acc) {
          int col = n0 + nt * 16 + lm;
          float bb = b_out[col];
#pragma unroll
          for (int rr = 0; rr < 4; ++rr) {
            int kk = mt * 16 + lq * 4 + rr;
            float eo = acc[rr] + bb;
            if (kk < nv) nsum[nt] += eo;
            float efv = ef[((size_t)base * KNBR + kk) * 128 + col];
            st_sw128(R1, kk, col, f2bf(eo + efv));
          }
        });
#pragma unroll
    for (int nt = 0; nt < 2; ++nt) {
      float v = nsum[nt];
      v += __shfl_xor(v, 16, 64);
      v += __shfl_xor(v, 32, 64);
      if (lq == 0) {
        int col = n0 + nt * 16 + lm;
        out_node[(size_t)base * 128 + col] =
            v + nf[(size_t)base * 128 + col];
      }
    }
  }
  __syncthreads();

  // ---- S7: EHN(R0) = LayerNorm(R) (scratch in R2) ----
  {
    float* scr = (float*)R2;
    int r = tid >> 3, sg = tid & 7;
    short8 xv[2];
    float s = 0.f, s2 = 0.f;
#pragma unroll
    for (int j = 0; j < 2; ++j) {
      int ch = sg * 2 + j;
      xv[j] = *(const short8*)(R1 + r * 128 + ((ch ^ (r & 7)) << 3));
#pragma unroll
      for (int e = 0; e < 8; ++e) {
        float x = bf2f(xv[j][e]);
        s += x;
        s2 = fmaf(x, x, s2);
      }
    }
    scr[r * 8 + sg] = s;
    scr[256 + r * 8 + sg] = s2;
    __syncthreads();
    if (tid < 32) {
      float ss = 0.f, q2 = 0.f;
#pragma unroll
      for (int i = 0; i < 8; ++i) { ss += scr[tid * 8 + i]; q2 += scr[256 + tid * 8 + i]; }
      float mn = ss * (1.f / 128.f);
      float vr = fmaf(-mn, mn, q2 * (1.f / 128.f));
      scr[512 + tid * 2] = mn;
      scr[512 + tid * 2 + 1] = rsqrtf(vr + 1e-5f);
    }
    __syncthreads();
    float mn = scr[512 + r * 2], rs = scr[512 + r * 2 + 1];
#pragma unroll
    for (int j = 0; j < 2; ++j) {
      int ch = sg * 2 + j;
      int c0 = ch * 8;
      float4 g0 = *(const float4*)(g_fe + c0);
      float4 g1 = *(const float4*)(g_fe + c0 + 4);
      float4 b0 = *(const float4*)(be_fe + c0);
      float4 b1 = *(const float4*)(be_fe + c0 + 4);
      const float* gp0 = (const float*)&g0;
      const float* gp1 = (const float*)&g1;
      const float* bp0 = (const float*)&b0;
      const float* bp1 = (const float*)&b1;
      short8 ov;
#pragma unroll
      for (int e = 0; e < 4; ++e) {
        ov[e] = f2bf(fmaf((bf2f(xv[j][e]) - mn) * rs, gp0[e], bp0[e]));
        ov[4 + e] = f2bf(fmaf((bf2f(xv[j][4 + e]) - mn) * rs, gp1[e], bp1[e]));
      }
      *(short8*)(R0 + r * 128 + ((ch ^ (r & 7)) << 3)) = ov;
    }
  }
  __syncthreads();

  // ---- S8: HID(R2..R3) = gelu(EHN @ WtE1 + be1), [32][256] swizzled ----
  {
    const int f0 = w * 64;
    wgemm_t<2, 4, 4>(
        [&](int r, int k, int q) { return ld_sw128(R0, r, k * 4 + q); },
        WtE1 + (size_t)f0 * 128,
        [&](int mt, int nt, f32x4 acc) {
          int colb = f0 + nt * 16 + lq * 4;
          float4 bb = *(const float4*)(be1 + colb);
          st_sw256_v4(R2, mt * 16 + lm, colb, pack_gelu4(acc, bb));
        });
  }
  __syncthreads();

  // ---- S9: out_edge = R + HID @ WtE2 + be2 (fp32 global stores), split-K ----
  {
    f32x4 ac[2][2];
#pragma unroll
    for (int mt = 0; mt < 2; ++mt)
#pragma unroll
      for (int nt = 0; nt < 2; ++nt) ac[mt][nt] = {0.f, 0.f, 0.f, 0.f};
    wgemm_pass<2, 2, 4>(
        [&](int r, int k, int q) { return ld_sw256(R2, r, k * 4 + q); },
        WtE2 + (size_t)n0 * 256, 256, ac);
    wgemm_pass<2, 2, 4>(
        [&](int r, int k, int q) { return ld_sw256(R2, r, 16 + k * 4 + q); },
        WtE2 + (size_t)n0 * 256 + 128, 256, ac);
#pragma unroll
    for (int mt = 0; mt < 2; ++mt)
#pragma unroll
      for (int nt = 0; nt < 2; ++nt) {
        int col = n0 + nt * 16 + lm;
        float bb = be2[col];
#pragma unroll
        for (int rr = 0; rr < 4; ++rr) {
          int m = mt * 16 + lq * 4 + rr;
          float rv = bf2f(R1[m * 128 + ((((col >> 3) ^ (m & 7))) << 3) + (col & 7)]);
          out_edge[((size_t)base * KNBR + m) * 128 + col] =
              rv + ac[mt][nt][rr] + bb;
        }
      }
  }
}

// ---------------- kernel 3: node FFN (16 nodes/block, MFMA) ----------------
__global__ __launch_bounds__(256, 4) void node_ffn_kernel(
    const float* __restrict__ nres, const float* __restrict__ g,
    const float* __restrict__ be, const short* __restrict__ WtN1,
    const float* __restrict__ bn1, const short* __restrict__ WtN2,
    const float* __restrict__ bn2, float* __restrict__ out) {
  __shared__ short lds[8192];
  short* EHN = lds;                    // [16][128] swizzled bf16 (2048 shorts)
  float* scr = (float*)(lds + 2048);   // 544 floats scratch
  short* HID = lds + 4096;             // [16][256] swizzled bf16 (4096 shorts)

  const int tid = threadIdx.x;
  const int w = tid >> 6;
  const int lane = tid & 63;
  const int lm = lane & 15, lq = lane >> 4;
  const int base = blockIdx.x * 16;
  const int n0 = w * 32;

  // LN from global node_res (fp32) -> EHN
  {
    int r = tid >> 4, sg = tid & 15;
    bool valid = (base + r) < N_NODES;
    float xf[8];
#pragma unroll
    for (int i = 0; i < 2; ++i) {
      float4 v = valid ? ((const float4*)(nres + (size_t)(base + r) * 128 + sg * 8))[i]
                       : make_float4(0.f, 0.f, 0.f, 0.f);
      xf[i * 4] = v.x; xf[i * 4 + 1] = v.y; xf[i * 4 + 2] = v.z; xf[i * 4 + 3] = v.w;
    }
    float s = 0.f, s2 = 0.f;
#pragma unroll
    for (int i = 0; i < 8; ++i) { s += xf[i]; s2 = fmaf(xf[i], xf[i], s2); }
    scr[r * 16 + sg] = s;
    scr[256 + r * 16 + sg] = s2;
    __syncthreads();
    if (tid < 16) {
      float ss = 0.f, q2 = 0.f;
#pragma unroll
      for (int i = 0; i < 16; ++i) { ss += scr[tid * 16 + i]; q2 += scr[256 + tid * 16 + i]; }
      float mn = ss * (1.f / 128.f);
      float vr = fmaf(-mn, mn, q2 * (1.f / 128.f));
      scr[512 + tid * 2] = mn;
      scr[512 + tid * 2 + 1] = rsqrtf(vr + 1e-5f);
    }
    __syncthreads();
    float mn = scr[512 + r * 2], rs = scr[512 + r * 2 + 1];
    int c0 = sg * 8;
    short8 ov;
#pragma unroll
    for (int e = 0; e < 8; ++e)
      ov[e] = f2bf(fmaf((xf[e] - mn) * rs, g[c0 + e], be[c0 + e]));
    *(short8*)(EHN + r * 128 + ((sg ^ (r & 7)) << 3)) = ov;
  }
  __syncthreads();

  // hidden = gelu(EHN @ WtN1 + bn1)
  {
    const int f0 = w * 64;
    wgemm_t<1, 4, 4>(
        [&](int r, int k, int q) { return ld_sw128(EHN, r, k * 4 + q); },
        WtN1 + (size_t)f0 * 128,
        [&](int mt, int nt, f32x4 acc) {
          int colb = f0 + nt * 16 + lq * 4;
          float4 bb = *(const float4*)(bn1 + colb);
          st_sw256_v4(HID, mt * 16 + lm, colb, pack_gelu4(acc, bb));
        });
  }
  __syncthreads();

  // out = node_res + hidden @ WtN2 + bn2 (split-K)
  {
    f32x4 ac[1][2];
    ac[0][0] = {0.f, 0.f, 0.f, 0.f};
    ac[0][1] = {0.f, 0.f, 0.f, 0.f};
    wgemm_pass<1, 2, 4>(
        [&](int r, int k, int q) { return ld_sw256(HID, r, k * 4 + q); },
        WtN2 + (size_t)n0 * 256, 256, ac);
    wgemm_pass<1, 2, 4>(
        [&](int r, int k, int q) { return ld_sw256(HID, r, 16 + k * 4 + q); },
        WtN2 + (size_t)n0 * 256 + 128, 256, ac);
#pragma unroll
    for (int nt = 0; nt < 2; ++nt) {
      int col = n0 + nt * 16 + lm;
      float bb = bn2[col];
#pragma unroll
      for (int rr = 0; rr < 4; ++rr) {
        int m = lq * 4 + rr;
        if (base + m < N_NODES) {
          float rv = nres[(size_t)(base + m) * 128 + col];
          out[(size_t)(base + m) * 128 + col] = rv + ac[0][nt][rr] + bb;
        }
      }
    }
  }
}

// ---------------- launch ----------------
extern "C" void kernel_launch(void* const* d_in, const int* in_sizes, int n_in,
                              void* d_out, int out_size, void* d_ws,
                              size_t ws_size, hipStream_t stream) {
  (void)in_sizes; (void)n_in; (void)out_size; (void)ws_size;
  const float* nf = (const float*)d_in[0];
  const float* ef = (const float*)d_in[1];
  const float* ea = (const float*)d_in[2];
  const int* nlist = (const int*)d_in[3];
  const int* nvalid = (const int*)d_in[4];
  const float* W_edge = (const float*)d_in[5];
  const float* b_edge = (const float*)d_in[6];
  const float* W_node = (const float*)d_in[7];
  const float* b_node = (const float*)d_in[8];
  const float* W_msg = (const float*)d_in[9];
  const float* b_msg = (const float*)d_in[10];
  const float* W_qkv = (const float*)d_in[11];
  const float* b_qkv = (const float*)d_in[12];
  const float* W_out = (const float*)d_in[13];
  const float* b_out = (const float*)d_in[14];
  const float* g_attn = (const float*)d_in[15];
  const float* be_attn = (const float*)d_in[16];
  const float* g_fn = (const float*)d_in[17];
  const float* be_fn = (const float*)d_in[18];
  const float* g_fe = (const float*)d_in[19];
  const float* be_fe = (const float*)d_in[20];
  const float* Wn1 = (const float*)d_in[21];
  const float* bn1 = (const float*)d_in[22];
  const float* Wn2 = (const float*)d_in[23];
  const float* bn2 = (const float*)d_in[24];
  const float* We1 = (const float*)d_in[25];
  const float* be1 = (const float*)d_in[26];
  const float* We2 = (const float*)d_in[27];
  const float* be2 = (const float*)d_in[28];

  short* ws0 = (short*)d_ws;           // node_hidden bf16 [N][128]
  short* wsW = ws0 + 1280000;          // transposed bf16 weights, 278528 elems
  short* WtE = wsW;
  short* WtN = wsW + 16384;
  short* WtM = wsW + 49152;
  short* WtQ = wsW + 81920;
  short* WtO = wsW + 131072;
  short* WtE1 = wsW + 147456;
  short* WtE2 = wsW + 180224;
  short* WtN1 = wsW + 212992;
  short* WtN2 = wsW + 245760;

  float* out_node = (float*)d_out;
  float* out_edge = out_node + (size_t)N_NODES * 128;

  WSrc wsrc;
  wsrc.p[0] = W_edge; wsrc.p[1] = W_node; wsrc.p[2] = W_msg;
  wsrc.p[3] = W_qkv;  wsrc.p[4] = W_out;  wsrc.p[5] = We1;
  wsrc.p[6] = We2;    wsrc.p[7] = Wn1;    wsrc.p[8] = Wn2;

  wprep_kernel<<<1088, 256, 0, stream>>>(wsrc, wsW);
  ln_in_kernel<<<(N_NODES + 31) / 32, 256, 0, stream>>>(nf, g_attn, be_attn, ws0);
  egab_main<<<N_NODES, 256, 0, stream>>>(
      nf, ef, ea, nlist, nvalid, b_edge, b_node, b_msg, b_qkv, b_out, g_fe,
      be_fe, be1, be2, WtE, WtN, WtM, WtQ, WtO, WtE1, WtE2, ws0, out_node,
      out_edge);
  node_ffn_kernel<<<(N_NODES + 15) / 16, 256, 0, stream>>>(
      out_node, g_fn, be_fn, WtN1, bn1, WtN2, bn2, out_node);
}